// Round 13
// baseline (127.326 us; speedup 1.0000x reference)
//
#include <hip/hip_runtime.h>

typedef unsigned int uint;
typedef unsigned short ushort;
typedef __attribute__((ext_vector_type(8))) short bf16x8;
typedef __attribute__((ext_vector_type(4))) float f32x4;

#define EPSF 1e-7f
#define ONE_M_EPS 0.99999988079071044921875f /* f32 nearest to 1-1e-7 */
#define ATANH_1ME 8.4056213f                 /* atanh(1-1e-7), f64-accurate */
#define Y2_CLIP 0.99999982f                  /* (1-1e-7)^2 */

__device__ __forceinline__ ushort f2bf(float f){
  union{float f;uint u;}x; x.f=f; uint u=x.u;
  return (ushort)((u + 0x7fffu + ((u>>16)&1u)) >> 16);
}
__device__ __forceinline__ float bf2f(ushort u){
  union{uint u;float f;}x; x.u = ((uint)u)<<16; return x.f;
}
__device__ __forceinline__ float atanh_c(float a){
  a = fminf(a, ONE_M_EPS);
  return 0.5f*__logf((1.f+a)/(1.f-a));
}
__device__ __forceinline__ float gelu_t(float v){
  return 0.5f*v*(1.f + tanhf(0.7978845608f*(v + 0.044715f*v*v*v)));
}

__device__ __forceinline__ float expmap_factor(float n2, float sc, float& r2){
  float n = sqrtf(n2);
  if (n < EPSF) { r2 = 0.f; return 0.f; }
  float mag = tanhf(sc*n)/sc;
  float f = mag/n;
  if (mag >= 1.f) { f *= ONE_M_EPS/mag; r2 = Y2_CLIP; }
  else r2 = mag*mag;
  return f;
}
__device__ __forceinline__ float roundtrip_factor(float tn2, float sc){
  float tn = sqrtf(tn2);
  if (tn < EPSF) return 0.f;
  float mag = tanhf(sc*tn)/sc;
  if (mag >= 1.f) {
    return ATANH_1ME / (sc * tn);
  } else {
    if (mag < EPSF) return 0.f;
    return (mag/tn) * (atanh_c(mag) / (sc * mag));
  }
}

// freqs[i] = 10000^(-i/32) = 10^(-i/8), f64-derived literals
__device__ __constant__ float FREQS[32] = {
  1.0f, 0.7498942093324559f, 0.5623413251903491f, 0.4216965034285822f,
  0.31622776601683794f, 0.23713737056616552f, 0.1778279410038923f, 0.13335214321633242f,
  0.1f, 0.07498942093324558f, 0.05623413251903491f, 0.04216965034285822f,
  0.03162277660168379f, 0.023713737056616554f, 0.01778279410038923f, 0.013335214321633242f,
  0.01f, 0.007498942093324559f, 0.005623413251903491f, 0.004216965034285822f,
  0.0031622776601683794f, 0.0023713737056616554f, 0.0017782794100389228f, 0.0013335214321633241f,
  0.001f, 0.0007498942093324558f, 0.0005623413251903491f, 0.0004216965034285822f,
  0.00031622776601683794f, 0.00023713737056616553f, 0.00017782794100389227f, 0.00013335214321633243f
};

// ---------------- block reductions (256 threads) ----------------
__device__ __forceinline__ float blkSum(float v, float* tmp){
  #pragma unroll
  for (int o=32;o>0;o>>=1) v += __shfl_xor(v, o, 64);
  int w = threadIdx.x >> 6;
  if ((threadIdx.x & 63) == 0) tmp[w] = v;
  __syncthreads();
  v = tmp[0]+tmp[1]+tmp[2]+tmp[3];
  __syncthreads();
  return v;
}
__device__ __forceinline__ float2 blkSum2(float a, float b, float* tmp){
  #pragma unroll
  for (int o=32;o>0;o>>=1){ a += __shfl_xor(a, o, 64); b += __shfl_xor(b, o, 64); }
  int w = threadIdx.x >> 6;
  if ((threadIdx.x & 63) == 0){ tmp[w] = a; tmp[4+w] = b; }
  __syncthreads();
  float2 r; r.x = tmp[0]+tmp[1]+tmp[2]+tmp[3]; r.y = tmp[4]+tmp[5]+tmp[6]+tmp[7];
  __syncthreads();
  return r;
}

// ---------------- fused front-end: 4 weight transposes + prep ----------------
__global__ __launch_bounds__(256) void k_pre(const float* __restrict__ qkv_w,
    const float* __restrict__ out_w, const float* __restrict__ ffn_w1,
    const float* __restrict__ ffn_w2, const float* __restrict__ x,
    const float* __restrict__ cg, const float* __restrict__ lns, const float* __restrict__ lnb,
    ushort* __restrict__ wq, ushort* __restrict__ wo,
    ushort* __restrict__ w1, ushort* __restrict__ w2, ushort* __restrict__ xtan){
  __shared__ float s[32][33];
  int b = blockIdx.x;
  if (b < 12288){
    const float* W; ushort* WT; int K, N;
    if (b < 3072){ W=qkv_w; WT=wq; K=1024; N=3072; }
    else if (b < 4096){ b-=3072; W=out_w; WT=wo; K=1024; N=1024; }
    else if (b < 8192){ b-=4096; W=ffn_w1; WT=w1; K=1024; N=4096; }
    else { b-=8192; W=ffn_w2; WT=w2; K=4096; N=1024; }
    int nbn = N >> 5;
    int n0 = (b % nbn)*32, k0 = (b / nbn)*32;
    int tx = threadIdx.x & 31, ty = threadIdx.x >> 5; // (32,8)
    #pragma unroll
    for (int i=0;i<4;i++)
      s[ty+8*i][tx] = W[(size_t)(k0+ty+8*i)*N + n0+tx];
    __syncthreads();
    #pragma unroll
    for (int i=0;i<4;i++)
      WT[(size_t)(n0+ty+8*i)*K + k0+tx] = f2bf(s[tx][ty+8*i]);
  } else {
    float* tmp = &s[0][0];
    int r = b - 12288, t = threadIdx.x;
    float c = cg[0];
    float sc = fmaxf(sqrtf(c), EPSF);
    float4 xv = ((const float4*)(x + (size_t)r*1024))[t];
    float n2 = blkSum(xv.x*xv.x + xv.y*xv.y + xv.z*xv.z + xv.w*xv.w, tmp);
    float n = sqrtf(n2);
    float f1 = (n < EPSF) ? 0.f : (atanh_c(n) / sc / n);
    float ux = xv.x*f1, uy = xv.y*f1, uz = xv.z*f1, uw = xv.w*f1;
    float2 s12 = blkSum2(ux+uy+uz+uw, ux*ux+uy*uy+uz*uz+uw*uw, tmp);
    float mu = s12.x*(1.f/1024.f);
    float var = s12.y*(1.f/1024.f) - mu*mu;
    float inv = rsqrtf(var + 1e-6f);
    float4 sv = ((const float4*)lns)[t];
    float4 bv = ((const float4*)lnb)[t];
    float ta = (ux-mu)*inv*sv.x + bv.x;
    float tb = (uy-mu)*inv*sv.y + bv.y;
    float tc = (uz-mu)*inv*sv.z + bv.z;
    float td = (uw-mu)*inv*sv.w + bv.w;
    float tn2 = blkSum(ta*ta+tb*tb+tc*tc+td*td, tmp);
    float f = roundtrip_factor(tn2, sc);
    ushort4 o; o.x=f2bf(ta*f); o.y=f2bf(tb*f); o.z=f2bf(tc*f); o.w=f2bf(td*f);
    ((ushort4*)(xtan + (size_t)r*1024))[t] = o;
  }
}

// ---------------- GEMM: C[M][N] = A[M][K](bf16) * Bt[N][K](bf16)^T + bias ----------------
// 3-buffer pipelined global_load_lds, counted vmcnt (T4), raw s_barrier, XOR-swizzled LDS,
// bijective XCD remap. BM=64, BN=64, 4 waves (each 16x64). 48KB LDS -> 3 blocks/CU.
// Ledger: stage = 4 gload_lds/wave. Prologue S0,S1. Iter t: wait vmcnt(4) (=S(t) retired,
// S(t+1) in flight) -> s_barrier (all waves' S(t) landed; separates compute(t-1) from
// re-staging b[(t+2)%3]=b[(t-1)%3]) -> stage(t+2) -> compute(t). Peeled last iter: vmcnt(0).
// EPI: 2 = gelu + bf16 out (z==0), 3 = f32 out at z*M*N (bias only z==0),
//      4 = qkv fused epilogue: bias + rope + expmap + hi/lo bf16 -> attn tiles (full-K, z==0)
template<int EPI>
__global__ __launch_bounds__(256) void k_gemm(const ushort* __restrict__ A,
    const ushort* __restrict__ Bt, const float* __restrict__ bias,
    void* __restrict__ C, int M, int N, int Kstride, int Kchunk,
    ushort* __restrict__ qhg = nullptr, ushort* __restrict__ qlg = nullptr,
    ushort* __restrict__ khg = nullptr, ushort* __restrict__ klg = nullptr,
    ushort* __restrict__ vhg = nullptr, float* __restrict__ q2g = nullptr,
    float* __restrict__ k2g = nullptr, const float* __restrict__ clog = nullptr){
  constexpr int NF = 4;
  __shared__ ushort As[3][64*64];
  __shared__ ushort Bs[3][64*64];
  const int tid = threadIdx.x;
  const int lane = tid & 63;
  const int wid = tid >> 6;
  const int ro = wid * 16;
  const int l15 = lane & 15, hi = lane >> 4;
  const int nwg = gridDim.x * gridDim.y;
  const int lin = blockIdx.y * gridDim.x + blockIdx.x;
  const int qq = nwg >> 3, rr = nwg & 7;
  const int xcd = lin & 7, ii = lin >> 3;
  const int swz = (xcd < rr) ? (xcd*(qq+1) + ii) : (rr*(qq+1) + (xcd-rr)*qq + ii);
  const int m0 = (swz % gridDim.y) * 64;
  const int n0 = (swz / gridDim.y) * 64;
  const int z = blockIdx.z;
  const int kbase = z * Kchunk;
  const int swr = (l15 & 7) << 3;

  f32x4 acc[NF];
  #pragma unroll
  for (int j=0;j<NF;j++) acc[j] = (f32x4){0.f,0.f,0.f,0.f};

  auto stage = [&](int buf, int koff){   // exactly 4 gload_lds instructions per wave
    #pragma unroll
    for (int r2=0;r2<2;r2++){
      int idx = r2*256 + tid;
      int row = idx >> 3, cc = idx & 7;
      int off = koff + ((cc ^ (row & 7)) << 3);
      int lo = (r2*256 + (tid & 192)) * 8;
      __builtin_amdgcn_global_load_lds((const __attribute__((address_space(1))) uint*)
          (A + (size_t)(m0+row)*Kstride + off),
          (__attribute__((address_space(3))) uint*)&As[buf][lo], 16, 0, 0);
      __builtin_amdgcn_global_load_lds((const __attribute__((address_space(1))) uint*)
          (Bt + (size_t)(n0+row)*Kstride + off),
          (__attribute__((address_space(3))) uint*)&Bs[buf][lo], 16, 0, 0);
    }
  };
  auto compute = [&](int buf){
    #pragma unroll
    for (int ks=0;ks<2;ks++){
      bf16x8 af, bfv[NF];
      int cb = (ks*32 + hi*8) ^ swr;
      af = *(const bf16x8*)&As[buf][(ro+l15)*64 + cb];
      #pragma unroll
      for (int n2=0;n2<NF;n2++) bfv[n2] = *(const bf16x8*)&Bs[buf][(n2*16+l15)*64 + cb];
      #pragma unroll
      for (int n2=0;n2<NF;n2++)
        acc[n2] = __builtin_amdgcn_mfma_f32_16x16x32_bf16(af, bfv[n2], acc[n2], 0, 0, 0);
    }
  };

  const int nt = Kchunk >> 6;   // >= 4 for all call sites
  stage(0, kbase);
  stage(1, kbase + 64);
  int t = 0;
  for (; t < nt-1; ++t){
    asm volatile("s_waitcnt vmcnt(4)" ::: "memory");
    __builtin_amdgcn_s_barrier();
    if (t+2 < nt) stage((t+2)%3, kbase + (t+2)*64);
    compute(t%3);
  }
  asm volatile("s_waitcnt vmcnt(0)" ::: "memory");
  __builtin_amdgcn_s_barrier();
  compute(t%3);

  if (EPI == 4){
    // qkv epilogue: wave covers 16 rows x one head-slice. type: 0=Q,1=K,2=V.
    const int type = n0 >> 10;
    const int h = (n0 & 1023) >> 6;
    float v[NF][4];
    #pragma unroll
    for (int n2=0;n2<NF;n2++){
      float bb = bias[n0 + n2*16 + l15];
      #pragma unroll
      for (int i=0;i<4;i++) v[n2][i] = acc[n2][i] + bb;
    }
    if (type < 2){
      const float cl = clog[h];
      const float chh = (cl > 20.f) ? cl : log1pf(__expf(cl));
      const float sch = fmaxf(sqrtf(chh), EPSF);
      ushort* hdst = (type==0) ? qhg : khg;
      ushort* ldst = (type==0) ? qlg : klg;
      float*  sdst = (type==0) ? q2g : k2g;
      #pragma unroll
      for (int i=0;i<4;i++){
        int gr = m0 + ro + hi*4 + i;
        int r = gr & 127, be = gr >> 7;
        float fr = (float)r;
        float sn, cn;
        __sincosf(fr * FREQS[l15], &sn, &cn);
        float a = v[0][i], b = v[2][i];
        v[0][i] = a*cn - b*sn; v[2][i] = a*sn + b*cn;
        __sincosf(fr * FREQS[l15+16], &sn, &cn);
        a = v[1][i]; b = v[3][i];
        v[1][i] = a*cn - b*sn; v[3][i] = a*sn + b*cn;
        float n2s = v[0][i]*v[0][i] + v[1][i]*v[1][i] + v[2][i]*v[2][i] + v[3][i]*v[3][i];
        #pragma unroll
        for (int o=1;o<16;o<<=1) n2s += __shfl_xor(n2s, o);
        float r2; float f = expmap_factor(n2s, sch, r2);
        size_t rowbase = ((size_t)(be*16 + h)*128 + r)*64;
        #pragma unroll
        for (int n2=0;n2<NF;n2++){
          float val = v[n2][i]*f;
          ushort hb = f2bf(val);
          ushort lb = f2bf(val - bf2f(hb));
          hdst[rowbase + n2*16 + l15] = hb;
          ldst[rowbase + n2*16 + l15] = lb;
        }
        if (l15 == 0) sdst[(size_t)(be*16+h)*128 + r] = r2;
      }
    } else {
      #pragma unroll
      for (int i=0;i<4;i++){
        int gr = m0 + ro + hi*4 + i;
        int r = gr & 127, be = gr >> 7;
        size_t rowbase = ((size_t)(be*16 + h)*128 + r)*64;
        #pragma unroll
        for (int n2=0;n2<NF;n2++)
          vhg[rowbase + n2*16 + l15] = f2bf(v[n2][i]);
      }
    }
    return;
  }

  #pragma unroll
  for (int n=0;n<NF;n++){
    int gc = n0 + n*16 + l15;
    float bb = (EPI == 3) ? (z == 0 ? bias[gc] : 0.f) : bias[gc];
    #pragma unroll
    for (int i=0;i<4;i++){
      int gr = m0 + ro + hi*4 + i;
      float v = acc[n][i] + bb;
      if (EPI == 2) v = gelu_t(v);
      if (EPI == 2) ((ushort*)C)[(size_t)gr*N + gc] = f2bf(v);
      else ((float*)C)[(size_t)z*M*N + (size_t)gr*N + gc] = v;
    }
  }
}

// ---------------- MFMA hyperbolic attention v6 ----------------
// grid (H=16, Be=8, qs=2), 256 threads (4 waves). Block: 64 q-rows x 128 kv.
// All prep in the qkv GEMM epilogue; staging is pure DMA (pre-swizzled global_load_lds) + V transpose.
__global__ __launch_bounds__(256) void k_attn6(const ushort* __restrict__ qhg,
    const ushort* __restrict__ qlg, const ushort* __restrict__ khg,
    const ushort* __restrict__ klg, const ushort* __restrict__ vhg,
    const float* __restrict__ q2g, const float* __restrict__ k2g,
    const float* __restrict__ c_logits, const float* __restrict__ geo,
    ushort* __restrict__ ao){
  __shared__ ushort Kh[128*64], Kl[128*64];   // after QK^T: Ph/Pl overlay [64][128]
  __shared__ ushort Vth[64*128];              // V^T [d][kv]
  __shared__ ushort Qh[64*64], Ql[64*64];
  __shared__ float k2s[128], q2s[64];
  const int h = blockIdx.x, be = blockIdx.y, qs = blockIdx.z;
  const int tid = threadIdx.x;
  const float cl = c_logits[h];
  const float ch = (cl > 20.f) ? cl : log1pf(__expf(cl));
  const float sc = fmaxf(sqrtf(ch), EPSF);
  const float gs = geo[h];
  const size_t tbase = (size_t)(be*16 + h)*8192;   // 128*64 elements per (be,h)

  // ---- K hi/lo staging ----
  #pragma unroll
  for (int r2=0;r2<4;r2++){
    int idx = r2*256 + tid;
    int row = idx >> 3, cc = idx & 7;
    int off = row*64 + ((cc ^ (row & 7)) << 3);
    int lo = (r2*256 + (tid & 192)) * 8;
    __builtin_amdgcn_global_load_lds((const __attribute__((address_space(1))) uint*)(khg + tbase + off),
        (__attribute__((address_space(3))) uint*)&Kh[lo], 16, 0, 0);
    __builtin_amdgcn_global_load_lds((const __attribute__((address_space(1))) uint*)(klg + tbase + off),
        (__attribute__((address_space(3))) uint*)&Kl[lo], 16, 0, 0);
  }
  // ---- Q hi/lo staging (rows qs*64 .. +64) ----
  #pragma unroll
  for (int r2=0;r2<2;r2++){
    int idx = r2*256 + tid;
    int row = idx >> 3, cc = idx & 7;
    int off = (qs*64 + row)*64 + ((cc ^ (row & 7)) << 3);
    int lo = (r2*256 + (tid & 192)) * 8;
    __builtin_amdgcn_global_load_lds((const __attribute__((address_space(1))) uint*)(qhg + tbase + off),
        (__attribute__((address_space(3))) uint*)&Qh[lo], 16, 0, 0);
    __builtin_amdgcn_global_load_lds((const __attribute__((address_space(1))) uint*)(qlg + tbase + off),
        (__attribute__((address_space(3))) uint*)&Ql[lo], 16, 0, 0);
  }
  // ---- V transpose staging + norm arrays ----
  if (tid < 128){
    int kv = tid;
    const uint4* src = (const uint4*)(vhg + tbase + kv*64);
    ushort v[64];
    #pragma unroll
    for (int c2=0;c2<8;c2++) *(uint4*)&v[c2*8] = src[c2];
    #pragma unroll
    for (int d=0; d<64; d++){
      int idx = d*128 + (((kv>>3) ^ (d&7))<<3) + (kv&7);
      Vth[idx] = v[d];
    }
    k2s[kv] = k2g[(size_t)(be*16+h)*128 + kv];
  } else if (tid < 192){
    int i2 = tid - 128;
    q2s[i2] = q2g[(size_t)(be*16+h)*128 + qs*64 + i2];
  }
  __syncthreads();

  // ---- QK^T: wave w handles q local rows [w*16, w*16+16) x 128 kv; 3-pass hi/lo ----
  const int lane = tid & 63, w = tid >> 6;
  const int l15 = lane & 15, hi4 = lane >> 4;
  f32x4 acc[8];
  #pragma unroll
  for (int nf=0;nf<8;nf++) acc[nf] = (f32x4){0.f,0.f,0.f,0.f};
  #pragma unroll
  for (int ks=0; ks<2; ks++){
    int qrowL = w*16 + l15;
    int qidx = qrowL*64 + (((ks*4 + hi4) ^ (qrowL&7))<<3);
    bf16x8 qh = *(const bf16x8*)&Qh[qidx];
    bf16x8 ql2 = *(const bf16x8*)&Ql[qidx];
    #pragma unroll
    for (int nf=0; nf<8; nf++){
      int krow = nf*16 + l15;
      int kidx = krow*64 + (((ks*4 + hi4) ^ (krow&7))<<3);
      bf16x8 kh = *(const bf16x8*)&Kh[kidx];
      bf16x8 kl2 = *(const bf16x8*)&Kl[kidx];
      acc[nf] = __builtin_amdgcn_mfma_f32_16x16x32_bf16(qh, kh, acc[nf], 0, 0, 0);
      acc[nf] = __builtin_amdgcn_mfma_f32_16x16x32_bf16(qh, kl2, acc[nf], 0, 0, 0);
      acc[nf] = __builtin_amdgcn_mfma_f32_16x16x32_bf16(ql2, kh, acc[nf], 0, 0, 0);
    }
  }
  __syncthreads();   // all K reads complete -> P may overlay Kh/Kl

  // ---- distance + softmax in registers (C-layout: row=(lane>>4)*4+i, col=lane&15) ----
  float q2v[4], Bfv[4];
  #pragma unroll
  for (int i=0;i<4;i++){ q2v[i] = q2s[w*16 + hi4*4 + i]; Bfv[i] = 1.f - ch*q2v[i]; }
  const float e2 = 2.f*ch;
  #pragma unroll
  for (int nf=0; nf<8; nf++){
    float k2 = k2s[nf*16 + l15];
    #pragma unroll
    for (int i=0;i<4;i++){
      float xy = acc[nf][i];
      float Af = 1.f + ch*k2 - e2*xy;
      float den = fmaxf(Af - ch*k2*Bfv[i], EPSF);
      float num2 = fmaxf(Af*(Af*q2v[i] - 2.f*Bfv[i]*xy) + Bfv[i]*Bfv[i]*k2, 0.f);
      float rn = sqrtf(num2)/den;
      rn = (rn >= 1.f) ? ONE_M_EPS : rn;
      float arg = fminf(sc*rn, ONE_M_EPS);
      float dd = __logf((1.f+arg)/(1.f-arg)) / sc;
      acc[nf][i] = -gs*dd;
    }
  }
  #pragma unroll
  for (int i=0;i<4;i++){
    float m = acc[0][i];
    #pragma unroll
    for (int nf=1;nf<8;nf++) m = fmaxf(m, acc[nf][i]);
    #pragma unroll
    for (int o=1;o<16;o<<=1) m = fmaxf(m, __shfl_xor(m, o));
    float l = 0.f;
    #pragma unroll
    for (int nf=0;nf<8;nf++){ float pp = __expf(acc[nf][i]-m); acc[nf][i] = pp; l += pp; }
    #pragma unroll
    for (int o=1;o<16;o<<=1) l += __shfl_xor(l, o);
    float inv = 1.f/l;
    #pragma unroll
    for (int nf=0;nf<8;nf++){
      float p = acc[nf][i]*inv;
      ushort ph = f2bf(p);
      ushort pl = f2bf(p - bf2f(ph));
      int row = w*16 + hi4*4 + i, col = nf*16 + l15;
      int idx = row*128 + (((col>>3) ^ (row&7))<<3) + (col&7);
      Kh[idx] = ph; Kl[idx] = pl;
    }
  }
  __syncthreads();

  // ---- PV: ao[64][64] via MFMA, 2-pass (Ph+Pl)*Vh ----
  f32x4 acc2[4];
  #pragma unroll
  for (int nf=0;nf<4;nf++) acc2[nf] = (f32x4){0.f,0.f,0.f,0.f};
  #pragma unroll
  for (int ks=0; ks<4; ks++){
    int prow = w*16 + l15;
    int pidx = prow*128 + (((ks*4 + hi4) ^ (prow&7))<<3);
    bf16x8 ph = *(const bf16x8*)&Kh[pidx];
    bf16x8 pl = *(const bf16x8*)&Kl[pidx];
    #pragma unroll
    for (int nf=0; nf<4; nf++){
      int vrow = nf*16 + l15;
      int vidx = vrow*128 + (((ks*4 + hi4) ^ (vrow&7))<<3);
      bf16x8 vh = *(const bf16x8*)&Vth[vidx];
      acc2[nf] = __builtin_amdgcn_mfma_f32_16x16x32_bf16(ph, vh, acc2[nf], 0, 0, 0);
      acc2[nf] = __builtin_amdgcn_mfma_f32_16x16x32_bf16(pl, vh, acc2[nf], 0, 0, 0);
    }
  }
  #pragma unroll
  for (int nf=0; nf<4; nf++)
    #pragma unroll
    for (int i=0;i<4;i++){
      int row = qs*64 + w*16 + hi4*4 + i;
      int col = nf*16 + l15;
      ao[(size_t)(be*128 + row)*1024 + h*64 + col] = f2bf(acc2[nf][i]);
    }
}

// ---------------- post-attention: mobius residual + LN2 roundtrip -> t (bf16) ----------------
__global__ __launch_bounds__(256) void k_postattn(const float* __restrict__ x,
    const float* __restrict__ proj, const float* __restrict__ cg,
    const float* __restrict__ lns, const float* __restrict__ lnb,
    float* __restrict__ xatt, ushort* __restrict__ tout){
  __shared__ float tmp[8];
  int r = blockIdx.x, t = threadIdx.x;
  float c = cg[0], sc = fmaxf(sqrtf(c), EPSF);
  float4 pa = ((const float4*)(proj + (size_t)r*1024))[t];
  float4 pb = ((const float4*)(proj + 1024*1024 + (size_t)r*1024))[t];
  float4 pc = ((const float4*)(proj + 2*1024*1024 + (size_t)r*1024))[t];
  float4 pd = ((const float4*)(proj + 3*1024*1024 + (size_t)r*1024))[t];
  float4 pv; pv.x=(pa.x+pb.x)+(pc.x+pd.x); pv.y=(pa.y+pb.y)+(pc.y+pd.y);
  pv.z=(pa.z+pb.z)+(pc.z+pd.z); pv.w=(pa.w+pb.w)+(pc.w+pd.w);
  float4 xv = ((const float4*)(x + (size_t)r*1024))[t];
  float pn2 = blkSum(pv.x*pv.x+pv.y*pv.y+pv.z*pv.z+pv.w*pv.w, tmp);
  float y2; float fy = expmap_factor(pn2, sc, y2);
  float ya = pv.x*fy, yb = pv.y*fy, yc = pv.z*fy, yd = pv.w*fy;
  float2 s = blkSum2(xv.x*xv.x+xv.y*xv.y+xv.z*xv.z+xv.w*xv.w,
                     xv.x*ya+xv.y*yb+xv.z*yc+xv.w*yd, tmp);
  float x2 = s.x, xy = s.y;
  float Af = 1.f + 2.f*c*xy + c*y2;
  float Bf = 1.f - c*x2;
  float den = fmaxf(1.f + 2.f*c*xy + c*c*x2*y2, EPSF);
  float num2 = fmaxf(Af*Af*x2 + 2.f*Af*Bf*xy + Bf*Bf*y2, 0.f);
  float rn = sqrtf(num2)/den;
  float fp = (rn >= 1.f) ? (ONE_M_EPS/fmaxf(rn,EPSF)) : 1.f;
  float xan = (rn >= 1.f) ? ONE_M_EPS : rn;
  float g = fp/den;
  float xa = (Af*xv.x + Bf*ya)*g;
  float xb = (Af*xv.y + Bf*yb)*g;
  float xc = (Af*xv.z + Bf*yc)*g;
  float xd = (Af*xv.w + Bf*yd)*g;
  float4 xo; xo.x=xa; xo.y=xb; xo.z=xc; xo.w=xd;
  ((float4*)(xatt + (size_t)r*1024))[t] = xo;
  float at = (rn >= 1.f) ? ATANH_1ME : atanh_c(xan);
  float fl = (xan < EPSF) ? 0.f : at / sc / fmaxf(xan, EPSF);
  float ux = xa*fl, uy = xb*fl, uz = xc*fl, uw = xd*fl;
  float2 s12 = blkSum2(ux+uy+uz+uw, ux*ux+uy*uy+uz*uz+uw*uw, tmp);
  float mu = s12.x*(1.f/1024.f);
  float var = s12.y*(1.f/1024.f) - mu*mu;
  float inv = rsqrtf(var + 1e-6f);
  float4 sv = ((const float4*)lns)[t];
  float4 bv = ((const float4*)lnb)[t];
  float ta = (ux-mu)*inv*sv.x + bv.x;
  float tb = (uy-mu)*inv*sv.y + bv.y;
  float tc = (uz-mu)*inv*sv.z + bv.z;
  float td = (uw-mu)*inv*sv.w + bv.w;
  float tn2 = blkSum(ta*ta+tb*tb+tc*tc+td*td, tmp);
  float f = roundtrip_factor(tn2, sc);
  ushort4 o; o.x=f2bf(ta*f); o.y=f2bf(tb*f); o.z=f2bf(tc*f); o.w=f2bf(td*f);
  ((ushort4*)(tout + (size_t)r*1024))[t] = o;
}

// ---------------- final: out = mobius_add(x_att, expmap0(tf)) ----------------
__global__ __launch_bounds__(256) void k_final(const float* __restrict__ xatt,
    const float* __restrict__ tf, const float* __restrict__ cg, float* __restrict__ out){
  __shared__ float tmp[8];
  int r = blockIdx.x, t = threadIdx.x;
  float c = cg[0], sc = fmaxf(sqrtf(c), EPSF);
  float4 fa = ((const float4*)(tf + (size_t)r*1024))[t];
  float4 fb = ((const float4*)(tf + 1024*1024 + (size_t)r*1024))[t];
  float4 fc = ((const float4*)(tf + 2*1024*1024 + (size_t)r*1024))[t];
  float4 fd = ((const float4*)(tf + 3*1024*1024 + (size_t)r*1024))[t];
  float4 fv; fv.x=(fa.x+fb.x)+(fc.x+fd.x); fv.y=(fa.y+fb.y)+(fc.y+fd.y);
  fv.z=(fa.z+fb.z)+(fc.z+fd.z); fv.w=(fa.w+fb.w)+(fc.w+fd.w);
  float4 xv = ((const float4*)(xatt + (size_t)r*1024))[t];
  float fn2 = blkSum(fv.x*fv.x+fv.y*fv.y+fv.z*fv.z+fv.w*fv.w, tmp);
  float y2; float fy = expmap_factor(fn2, sc, y2);
  float ya = fv.x*fy, yb = fv.y*fy, yc = fv.z*fy, yd = fv.w*fy;
  float2 s = blkSum2(xv.x*xv.x+xv.y*xv.y+xv.z*xv.z+xv.w*xv.w,
                     xv.x*ya+xv.y*yb+xv.z*yc+xv.w*yd, tmp);
  float x2 = s.x, xy = s.y;
  float Af = 1.f + 2.f*c*xy + c*y2;
  float Bf = 1.f - c*x2;
  float den = fmaxf(1.f + 2.f*c*xy + c*c*x2*y2, EPSF);
  float num2 = fmaxf(Af*Af*x2 + 2.f*Af*Bf*xy + Bf*Bf*y2, 0.f);
  float rn = sqrtf(num2)/den;
  float fp = (rn >= 1.f) ? (ONE_M_EPS/fmaxf(rn,EPSF)) : 1.f;
  float g = fp/den;
  float4 o;
  o.x = (Af*xv.x + Bf*ya)*g;
  o.y = (Af*xv.y + Bf*yb)*g;
  o.z = (Af*xv.z + Bf*yc)*g;
  o.w = (Af*xv.w + Bf*yd)*g;
  ((float4*)(out + (size_t)r*1024))[t] = o;
}

extern "C" void kernel_launch(void* const* d_in, const int* in_sizes, int n_in,
                              void* d_out, int out_size, void* d_ws, size_t ws_size,
                              hipStream_t stream){
  (void)in_sizes; (void)n_in; (void)out_size; (void)ws_size;
  const float* x     = (const float*)d_in[0];
  const float* cg    = (const float*)d_in[1];
  const float* qkv_w = (const float*)d_in[2];
  const float* qkv_b = (const float*)d_in[3];
  const float* out_w = (const float*)d_in[4];
  const float* out_b = (const float*)d_in[5];
  const float* ffn_w1= (const float*)d_in[6];
  const float* ffn_b1= (const float*)d_in[7];
  const float* ffn_w2= (const float*)d_in[8];
  const float* ffn_b2= (const float*)d_in[9];
  const float* ln1s  = (const float*)d_in[10];
  const float* ln1b  = (const float*)d_in[11];
  const float* ln2s  = (const float*)d_in[12];
  const float* ln2b  = (const float*)d_in[13];
  const float* clog  = (const float*)d_in[14];
  const float* geo   = (const float*)d_in[15];

  char* p = (char*)d_ws;
  auto take = [&](size_t n){ char* r = p; p += (n + 255) & ~(size_t)255; return r; };
  ushort* wt_qkv  = (ushort*)take((size_t)3072*1024*2);
  ushort* wt_out  = (ushort*)take((size_t)1024*1024*2);
  ushort* wt_ffn1 = (ushort*)take((size_t)4096*1024*2);
  ushort* wt_ffn2 = (ushort*)take((size_t)1024*4096*2);
  float*  bufA    = (float*)take((size_t)1024*4096*4);  // ffn1 bf16 out region
  ushort* bufB    = (ushort*)take((size_t)1024*1024*2); // x_tan ; later ao
  float*  bufC    = (float*)take((size_t)4*1024*1024*4);// split-K partials (4x 4MB)
  float*  xatt    = (float*)take((size_t)1024*1024*4);
  ushort* tbuf    = (ushort*)take((size_t)1024*1024*2);
  ushort* qhg     = (ushort*)take((size_t)1024*1024*2); // [be][h][128][64]
  ushort* qlg     = (ushort*)take((size_t)1024*1024*2);
  ushort* khg     = (ushort*)take((size_t)1024*1024*2);
  ushort* klg     = (ushort*)take((size_t)1024*1024*2);
  ushort* vhg     = (ushort*)take((size_t)1024*1024*2);
  float*  q2g     = (float*)take((size_t)16384*4);
  float*  k2g     = (float*)take((size_t)16384*4);

  k_pre<<<13312, 256, 0, stream>>>(qkv_w, out_w, ffn_w1, ffn_w2, x, cg, ln1s, ln1b,
                                   wt_qkv, wt_out, wt_ffn1, wt_ffn2, bufB);
  // qkv: BM=64 full-K (768 blocks = 3/CU) with fused rope/expmap/hi-lo epilogue -> attn tiles
  k_gemm<4><<<dim3(48,16,1), 256, 0, stream>>>(bufB, wt_qkv, qkv_b, nullptr, 1024, 3072, 1024, 1024,
                                               qhg, qlg, khg, klg, vhg, q2g, k2g, clog);
  k_attn6<<<dim3(16,8,2), 256, 0, stream>>>(qhg, qlg, khg, klg, vhg, q2g, k2g, clog, geo, bufB);
  // out-proj: BM=64 split-K4 (1024 blocks)
  k_gemm<3><<<dim3(16,16,4), 256, 0, stream>>>(bufB, wt_out, out_b, (void*)bufC, 1024, 1024, 1024, 256);
  k_postattn<<<1024, 256, 0, stream>>>(x, bufC, cg, ln2s, ln2b, xatt, tbuf);
  // ffn1: BM=64 full-K gelu (1024 blocks)
  k_gemm<2><<<dim3(64,16,1), 256, 0, stream>>>(tbuf, wt_ffn1, ffn_b1, (void*)bufA, 1024, 4096, 1024, 1024);
  // ffn2: BM=64 split-K4 (1024 blocks)
  k_gemm<3><<<dim3(16,16,4), 256, 0, stream>>>((const ushort*)bufA, wt_ffn2, ffn_b2, (void*)bufC, 1024, 1024, 4096, 1024);
  k_final<<<1024, 256, 0, stream>>>(xatt, bufC, cg, (float*)d_out);
}

// Round 14
// 110.876 us; speedup vs baseline: 1.1484x; 1.1484x over previous
//
#include <hip/hip_runtime.h>

typedef unsigned int uint;
typedef unsigned short ushort;
typedef __attribute__((ext_vector_type(8))) short bf16x8;
typedef __attribute__((ext_vector_type(4))) float f32x4;

#define EPSF 1e-7f
#define ONE_M_EPS 0.99999988079071044921875f /* f32 nearest to 1-1e-7 */
#define ATANH_1ME 8.4056213f                 /* atanh(1-1e-7), f64-accurate */
#define Y2_CLIP 0.99999982f                  /* (1-1e-7)^2 */

__device__ __forceinline__ ushort f2bf(float f){
  union{float f;uint u;}x; x.f=f; uint u=x.u;
  return (ushort)((u + 0x7fffu + ((u>>16)&1u)) >> 16);
}
__device__ __forceinline__ float bf2f(ushort u){
  union{uint u;float f;}x; x.u = ((uint)u)<<16; return x.f;
}
__device__ __forceinline__ float atanh_c(float a){
  a = fminf(a, ONE_M_EPS);
  return 0.5f*__logf((1.f+a)/(1.f-a));
}
__device__ __forceinline__ float gelu_t(float v){
  return 0.5f*v*(1.f + tanhf(0.7978845608f*(v + 0.044715f*v*v*v)));
}

__device__ __forceinline__ float expmap_factor(float n2, float sc, float& r2){
  float n = sqrtf(n2);
  if (n < EPSF) { r2 = 0.f; return 0.f; }
  float mag = tanhf(sc*n)/sc;
  float f = mag/n;
  if (mag >= 1.f) { f *= ONE_M_EPS/mag; r2 = Y2_CLIP; }
  else r2 = mag*mag;
  return f;
}
__device__ __forceinline__ float roundtrip_factor(float tn2, float sc){
  float tn = sqrtf(tn2);
  if (tn < EPSF) return 0.f;
  float mag = tanhf(sc*tn)/sc;
  if (mag >= 1.f) {
    return ATANH_1ME / (sc * tn);
  } else {
    if (mag < EPSF) return 0.f;
    return (mag/tn) * (atanh_c(mag) / (sc * mag));
  }
}

// freqs[i] = 10000^(-i/32) = 10^(-i/8), f64-derived literals
__device__ __constant__ float FREQS[32] = {
  1.0f, 0.7498942093324559f, 0.5623413251903491f, 0.4216965034285822f,
  0.31622776601683794f, 0.23713737056616552f, 0.1778279410038923f, 0.13335214321633242f,
  0.1f, 0.07498942093324558f, 0.05623413251903491f, 0.04216965034285822f,
  0.03162277660168379f, 0.023713737056616554f, 0.01778279410038923f, 0.013335214321633242f,
  0.01f, 0.007498942093324559f, 0.005623413251903491f, 0.004216965034285822f,
  0.0031622776601683794f, 0.0023713737056616554f, 0.0017782794100389228f, 0.0013335214321633241f,
  0.001f, 0.0007498942093324558f, 0.0005623413251903491f, 0.0004216965034285822f,
  0.00031622776601683794f, 0.00023713737056616553f, 0.00017782794100389227f, 0.00013335214321633243f
};

// ---------------- block reductions (256 threads) ----------------
__device__ __forceinline__ float blkSum(float v, float* tmp){
  #pragma unroll
  for (int o=32;o>0;o>>=1) v += __shfl_xor(v, o, 64);
  int w = threadIdx.x >> 6;
  if ((threadIdx.x & 63) == 0) tmp[w] = v;
  __syncthreads();
  v = tmp[0]+tmp[1]+tmp[2]+tmp[3];
  __syncthreads();
  return v;
}
__device__ __forceinline__ float2 blkSum2(float a, float b, float* tmp){
  #pragma unroll
  for (int o=32;o>0;o>>=1){ a += __shfl_xor(a, o, 64); b += __shfl_xor(b, o, 64); }
  int w = threadIdx.x >> 6;
  if ((threadIdx.x & 63) == 0){ tmp[w] = a; tmp[4+w] = b; }
  __syncthreads();
  float2 r; r.x = tmp[0]+tmp[1]+tmp[2]+tmp[3]; r.y = tmp[4]+tmp[5]+tmp[6]+tmp[7];
  __syncthreads();
  return r;
}

// ---------------- fused front-end: 4 weight transposes + prep ----------------
__global__ __launch_bounds__(256) void k_pre(const float* __restrict__ qkv_w,
    const float* __restrict__ out_w, const float* __restrict__ ffn_w1,
    const float* __restrict__ ffn_w2, const float* __restrict__ x,
    const float* __restrict__ cg, const float* __restrict__ lns, const float* __restrict__ lnb,
    ushort* __restrict__ wq, ushort* __restrict__ wo,
    ushort* __restrict__ w1, ushort* __restrict__ w2, ushort* __restrict__ xtan){
  __shared__ float s[32][33];
  int b = blockIdx.x;
  if (b < 12288){
    const float* W; ushort* WT; int K, N;
    if (b < 3072){ W=qkv_w; WT=wq; K=1024; N=3072; }
    else if (b < 4096){ b-=3072; W=out_w; WT=wo; K=1024; N=1024; }
    else if (b < 8192){ b-=4096; W=ffn_w1; WT=w1; K=1024; N=4096; }
    else { b-=8192; W=ffn_w2; WT=w2; K=4096; N=1024; }
    int nbn = N >> 5;
    int n0 = (b % nbn)*32, k0 = (b / nbn)*32;
    int tx = threadIdx.x & 31, ty = threadIdx.x >> 5; // (32,8)
    #pragma unroll
    for (int i=0;i<4;i++)
      s[ty+8*i][tx] = W[(size_t)(k0+ty+8*i)*N + n0+tx];
    __syncthreads();
    #pragma unroll
    for (int i=0;i<4;i++)
      WT[(size_t)(n0+ty+8*i)*K + k0+tx] = f2bf(s[tx][ty+8*i]);
  } else {
    float* tmp = &s[0][0];
    int r = b - 12288, t = threadIdx.x;
    float c = cg[0];
    float sc = fmaxf(sqrtf(c), EPSF);
    float4 xv = ((const float4*)(x + (size_t)r*1024))[t];
    float n2 = blkSum(xv.x*xv.x + xv.y*xv.y + xv.z*xv.z + xv.w*xv.w, tmp);
    float n = sqrtf(n2);
    float f1 = (n < EPSF) ? 0.f : (atanh_c(n) / sc / n);
    float ux = xv.x*f1, uy = xv.y*f1, uz = xv.z*f1, uw = xv.w*f1;
    float2 s12 = blkSum2(ux+uy+uz+uw, ux*ux+uy*uy+uz*uz+uw*uw, tmp);
    float mu = s12.x*(1.f/1024.f);
    float var = s12.y*(1.f/1024.f) - mu*mu;
    float inv = rsqrtf(var + 1e-6f);
    float4 sv = ((const float4*)lns)[t];
    float4 bv = ((const float4*)lnb)[t];
    float ta = (ux-mu)*inv*sv.x + bv.x;
    float tb = (uy-mu)*inv*sv.y + bv.y;
    float tc = (uz-mu)*inv*sv.z + bv.z;
    float td = (uw-mu)*inv*sv.w + bv.w;
    float tn2 = blkSum(ta*ta+tb*tb+tc*tc+td*td, tmp);
    float f = roundtrip_factor(tn2, sc);
    ushort4 o; o.x=f2bf(ta*f); o.y=f2bf(tb*f); o.z=f2bf(tc*f); o.w=f2bf(td*f);
    ((ushort4*)(xtan + (size_t)r*1024))[t] = o;
  }
}

// ---------------- GEMM: C[M][N] = A[M][K](bf16) * Bt[N][K](bf16)^T + bias ----------------
// 2-phase pipelined global_load_lds double-buffer, XOR-swizzled LDS, bijective XCD remap.
// BM=64, BN=64, 4 waves (each 16x64). 32KB LDS -> 4 blocks/CU (16 waves/CU TLP).
// EPI: 2 = gelu + bf16 out (z==0), 3 = f32 out at z*M*N (bias only z==0),
//      4 = qkv fused epilogue: bias + rope + expmap + hi/lo bf16 -> attn tiles (full-K, z==0)
template<int EPI>
__global__ __launch_bounds__(256) void k_gemm(const ushort* __restrict__ A,
    const ushort* __restrict__ Bt, const float* __restrict__ bias,
    void* __restrict__ C, int M, int N, int Kstride, int Kchunk,
    ushort* __restrict__ qhg = nullptr, ushort* __restrict__ qlg = nullptr,
    ushort* __restrict__ khg = nullptr, ushort* __restrict__ klg = nullptr,
    ushort* __restrict__ vhg = nullptr, float* __restrict__ q2g = nullptr,
    float* __restrict__ k2g = nullptr, const float* __restrict__ clog = nullptr){
  constexpr int NF = 4;
  __shared__ ushort As[2][64*64];
  __shared__ ushort Bs[2][64*64];
  const int tid = threadIdx.x;
  const int lane = tid & 63;
  const int wid = tid >> 6;
  const int ro = wid * 16;
  const int l15 = lane & 15, hi = lane >> 4;
  const int nwg = gridDim.x * gridDim.y;
  const int lin = blockIdx.y * gridDim.x + blockIdx.x;
  const int qq = nwg >> 3, rr = nwg & 7;
  const int xcd = lin & 7, ii = lin >> 3;
  const int swz = (xcd < rr) ? (xcd*(qq+1) + ii) : (rr*(qq+1) + (xcd-rr)*qq + ii);
  const int m0 = (swz % gridDim.y) * 64;
  const int n0 = (swz / gridDim.y) * 64;
  const int z = blockIdx.z;
  const int kbase = z * Kchunk;
  const int swr = (l15 & 7) << 3;

  f32x4 acc[NF];
  #pragma unroll
  for (int j=0;j<NF;j++) acc[j] = (f32x4){0.f,0.f,0.f,0.f};

  auto stage = [&](int buf, int koff){
    #pragma unroll
    for (int r2=0;r2<2;r2++){
      int idx = r2*256 + tid;
      int row = idx >> 3, cc = idx & 7;
      int off = koff + ((cc ^ (row & 7)) << 3);
      int lo = (r2*256 + (tid & 192)) * 8;
      __builtin_amdgcn_global_load_lds((const __attribute__((address_space(1))) uint*)
          (A + (size_t)(m0+row)*Kstride + off),
          (__attribute__((address_space(3))) uint*)&As[buf][lo], 16, 0, 0);
      __builtin_amdgcn_global_load_lds((const __attribute__((address_space(1))) uint*)
          (Bt + (size_t)(n0+row)*Kstride + off),
          (__attribute__((address_space(3))) uint*)&Bs[buf][lo], 16, 0, 0);
    }
  };
  auto compute = [&](int buf){
    #pragma unroll
    for (int ks=0;ks<2;ks++){
      bf16x8 af, bfv[NF];
      int cb = (ks*32 + hi*8) ^ swr;
      af = *(const bf16x8*)&As[buf][(ro+l15)*64 + cb];
      #pragma unroll
      for (int n2=0;n2<NF;n2++) bfv[n2] = *(const bf16x8*)&Bs[buf][(n2*16+l15)*64 + cb];
      #pragma unroll
      for (int n2=0;n2<NF;n2++)
        acc[n2] = __builtin_amdgcn_mfma_f32_16x16x32_bf16(af, bfv[n2], acc[n2], 0, 0, 0);
    }
  };

  const int nt = Kchunk >> 6;
  stage(0, kbase);
  __syncthreads();
  int cur = 0;
  for (int t = 1; t < nt; ++t){
    stage(cur ^ 1, kbase + t*64);
    compute(cur);
    __syncthreads();
    cur ^= 1;
  }
  compute(cur);

  if (EPI == 4){
    // qkv epilogue: wave covers 16 rows x one head-slice. type: 0=Q,1=K,2=V.
    const int type = n0 >> 10;
    const int h = (n0 & 1023) >> 6;
    float v[NF][4];
    #pragma unroll
    for (int n2=0;n2<NF;n2++){
      float bb = bias[n0 + n2*16 + l15];
      #pragma unroll
      for (int i=0;i<4;i++) v[n2][i] = acc[n2][i] + bb;
    }
    if (type < 2){
      const float cl = clog[h];
      const float chh = (cl > 20.f) ? cl : log1pf(__expf(cl));
      const float sch = fmaxf(sqrtf(chh), EPSF);
      ushort* hdst = (type==0) ? qhg : khg;
      ushort* ldst = (type==0) ? qlg : klg;
      float*  sdst = (type==0) ? q2g : k2g;
      #pragma unroll
      for (int i=0;i<4;i++){
        int gr = m0 + ro + hi*4 + i;
        int r = gr & 127, be = gr >> 7;
        float fr = (float)r;
        float sn, cn;
        __sincosf(fr * FREQS[l15], &sn, &cn);
        float a = v[0][i], b = v[2][i];
        v[0][i] = a*cn - b*sn; v[2][i] = a*sn + b*cn;
        __sincosf(fr * FREQS[l15+16], &sn, &cn);
        a = v[1][i]; b = v[3][i];
        v[1][i] = a*cn - b*sn; v[3][i] = a*sn + b*cn;
        float n2s = v[0][i]*v[0][i] + v[1][i]*v[1][i] + v[2][i]*v[2][i] + v[3][i]*v[3][i];
        #pragma unroll
        for (int o=1;o<16;o<<=1) n2s += __shfl_xor(n2s, o);
        float r2; float f = expmap_factor(n2s, sch, r2);
        size_t rowbase = ((size_t)(be*16 + h)*128 + r)*64;
        #pragma unroll
        for (int n2=0;n2<NF;n2++){
          float val = v[n2][i]*f;
          ushort hb = f2bf(val);
          ushort lb = f2bf(val - bf2f(hb));
          hdst[rowbase + n2*16 + l15] = hb;
          ldst[rowbase + n2*16 + l15] = lb;
        }
        if (l15 == 0) sdst[(size_t)(be*16+h)*128 + r] = r2;
      }
    } else {
      #pragma unroll
      for (int i=0;i<4;i++){
        int gr = m0 + ro + hi*4 + i;
        int r = gr & 127, be = gr >> 7;
        size_t rowbase = ((size_t)(be*16 + h)*128 + r)*64;
        #pragma unroll
        for (int n2=0;n2<NF;n2++)
          vhg[rowbase + n2*16 + l15] = f2bf(v[n2][i]);
      }
    }
    return;
  }

  #pragma unroll
  for (int n=0;n<NF;n++){
    int gc = n0 + n*16 + l15;
    float bb = (EPI == 3) ? (z == 0 ? bias[gc] : 0.f) : bias[gc];
    #pragma unroll
    for (int i=0;i<4;i++){
      int gr = m0 + ro + hi*4 + i;
      float v = acc[n][i] + bb;
      if (EPI == 2) v = gelu_t(v);
      if (EPI == 2) ((ushort*)C)[(size_t)gr*N + gc] = f2bf(v);
      else ((float*)C)[(size_t)z*M*N + (size_t)gr*N + gc] = v;
    }
  }
}

// ---------------- MFMA hyperbolic attention v6 ----------------
// grid (H=16, Be=8, qs=2), 256 threads (4 waves). Block: 64 q-rows x 128 kv.
// All prep in the qkv GEMM epilogue; staging is pure DMA (pre-swizzled global_load_lds) + V transpose.
__global__ __launch_bounds__(256) void k_attn6(const ushort* __restrict__ qhg,
    const ushort* __restrict__ qlg, const ushort* __restrict__ khg,
    const ushort* __restrict__ klg, const ushort* __restrict__ vhg,
    const float* __restrict__ q2g, const float* __restrict__ k2g,
    const float* __restrict__ c_logits, const float* __restrict__ geo,
    ushort* __restrict__ ao){
  __shared__ ushort Kh[128*64], Kl[128*64];   // after QK^T: Ph/Pl overlay [64][128]
  __shared__ ushort Vth[64*128];              // V^T [d][kv]
  __shared__ ushort Qh[64*64], Ql[64*64];
  __shared__ float k2s[128], q2s[64];
  const int h = blockIdx.x, be = blockIdx.y, qs = blockIdx.z;
  const int tid = threadIdx.x;
  const float cl = c_logits[h];
  const float ch = (cl > 20.f) ? cl : log1pf(__expf(cl));
  const float sc = fmaxf(sqrtf(ch), EPSF);
  const float gs = geo[h];
  const size_t tbase = (size_t)(be*16 + h)*8192;   // 128*64 elements per (be,h)

  // ---- K hi/lo staging ----
  #pragma unroll
  for (int r2=0;r2<4;r2++){
    int idx = r2*256 + tid;
    int row = idx >> 3, cc = idx & 7;
    int off = row*64 + ((cc ^ (row & 7)) << 3);
    int lo = (r2*256 + (tid & 192)) * 8;
    __builtin_amdgcn_global_load_lds((const __attribute__((address_space(1))) uint*)(khg + tbase + off),
        (__attribute__((address_space(3))) uint*)&Kh[lo], 16, 0, 0);
    __builtin_amdgcn_global_load_lds((const __attribute__((address_space(1))) uint*)(klg + tbase + off),
        (__attribute__((address_space(3))) uint*)&Kl[lo], 16, 0, 0);
  }
  // ---- Q hi/lo staging (rows qs*64 .. +64) ----
  #pragma unroll
  for (int r2=0;r2<2;r2++){
    int idx = r2*256 + tid;
    int row = idx >> 3, cc = idx & 7;
    int off = (qs*64 + row)*64 + ((cc ^ (row & 7)) << 3);
    int lo = (r2*256 + (tid & 192)) * 8;
    __builtin_amdgcn_global_load_lds((const __attribute__((address_space(1))) uint*)(qhg + tbase + off),
        (__attribute__((address_space(3))) uint*)&Qh[lo], 16, 0, 0);
    __builtin_amdgcn_global_load_lds((const __attribute__((address_space(1))) uint*)(qlg + tbase + off),
        (__attribute__((address_space(3))) uint*)&Ql[lo], 16, 0, 0);
  }
  // ---- V transpose staging + norm arrays ----
  if (tid < 128){
    int kv = tid;
    const uint4* src = (const uint4*)(vhg + tbase + kv*64);
    ushort v[64];
    #pragma unroll
    for (int c2=0;c2<8;c2++) *(uint4*)&v[c2*8] = src[c2];
    #pragma unroll
    for (int d=0; d<64; d++){
      int idx = d*128 + (((kv>>3) ^ (d&7))<<3) + (kv&7);
      Vth[idx] = v[d];
    }
    k2s[kv] = k2g[(size_t)(be*16+h)*128 + kv];
  } else if (tid < 192){
    int i2 = tid - 128;
    q2s[i2] = q2g[(size_t)(be*16+h)*128 + qs*64 + i2];
  }
  __syncthreads();

  // ---- QK^T: wave w handles q local rows [w*16, w*16+16) x 128 kv; 3-pass hi/lo ----
  const int lane = tid & 63, w = tid >> 6;
  const int l15 = lane & 15, hi4 = lane >> 4;
  f32x4 acc[8];
  #pragma unroll
  for (int nf=0;nf<8;nf++) acc[nf] = (f32x4){0.f,0.f,0.f,0.f};
  #pragma unroll
  for (int ks=0; ks<2; ks++){
    int qrowL = w*16 + l15;
    int qidx = qrowL*64 + (((ks*4 + hi4) ^ (qrowL&7))<<3);
    bf16x8 qh = *(const bf16x8*)&Qh[qidx];
    bf16x8 ql2 = *(const bf16x8*)&Ql[qidx];
    #pragma unroll
    for (int nf=0; nf<8; nf++){
      int krow = nf*16 + l15;
      int kidx = krow*64 + (((ks*4 + hi4) ^ (krow&7))<<3);
      bf16x8 kh = *(const bf16x8*)&Kh[kidx];
      bf16x8 kl2 = *(const bf16x8*)&Kl[kidx];
      acc[nf] = __builtin_amdgcn_mfma_f32_16x16x32_bf16(qh, kh, acc[nf], 0, 0, 0);
      acc[nf] = __builtin_amdgcn_mfma_f32_16x16x32_bf16(qh, kl2, acc[nf], 0, 0, 0);
      acc[nf] = __builtin_amdgcn_mfma_f32_16x16x32_bf16(ql2, kh, acc[nf], 0, 0, 0);
    }
  }
  __syncthreads();   // all K reads complete -> P may overlay Kh/Kl

  // ---- distance + softmax in registers (C-layout: row=(lane>>4)*4+i, col=lane&15) ----
  float q2v[4], Bfv[4];
  #pragma unroll
  for (int i=0;i<4;i++){ q2v[i] = q2s[w*16 + hi4*4 + i]; Bfv[i] = 1.f - ch*q2v[i]; }
  const float e2 = 2.f*ch;
  #pragma unroll
  for (int nf=0; nf<8; nf++){
    float k2 = k2s[nf*16 + l15];
    #pragma unroll
    for (int i=0;i<4;i++){
      float xy = acc[nf][i];
      float Af = 1.f + ch*k2 - e2*xy;
      float den = fmaxf(Af - ch*k2*Bfv[i], EPSF);
      float num2 = fmaxf(Af*(Af*q2v[i] - 2.f*Bfv[i]*xy) + Bfv[i]*Bfv[i]*k2, 0.f);
      float rn = sqrtf(num2)/den;
      rn = (rn >= 1.f) ? ONE_M_EPS : rn;
      float arg = fminf(sc*rn, ONE_M_EPS);
      float dd = __logf((1.f+arg)/(1.f-arg)) / sc;
      acc[nf][i] = -gs*dd;
    }
  }
  #pragma unroll
  for (int i=0;i<4;i++){
    float m = acc[0][i];
    #pragma unroll
    for (int nf=1;nf<8;nf++) m = fmaxf(m, acc[nf][i]);
    #pragma unroll
    for (int o=1;o<16;o<<=1) m = fmaxf(m, __shfl_xor(m, o));
    float l = 0.f;
    #pragma unroll
    for (int nf=0;nf<8;nf++){ float pp = __expf(acc[nf][i]-m); acc[nf][i] = pp; l += pp; }
    #pragma unroll
    for (int o=1;o<16;o<<=1) l += __shfl_xor(l, o);
    float inv = 1.f/l;
    #pragma unroll
    for (int nf=0;nf<8;nf++){
      float p = acc[nf][i]*inv;
      ushort ph = f2bf(p);
      ushort pl = f2bf(p - bf2f(ph));
      int row = w*16 + hi4*4 + i, col = nf*16 + l15;
      int idx = row*128 + (((col>>3) ^ (row&7))<<3) + (col&7);
      Kh[idx] = ph; Kl[idx] = pl;
    }
  }
  __syncthreads();

  // ---- PV: ao[64][64] via MFMA, 2-pass (Ph+Pl)*Vh ----
  f32x4 acc2[4];
  #pragma unroll
  for (int nf=0;nf<4;nf++) acc2[nf] = (f32x4){0.f,0.f,0.f,0.f};
  #pragma unroll
  for (int ks=0; ks<4; ks++){
    int prow = w*16 + l15;
    int pidx = prow*128 + (((ks*4 + hi4) ^ (prow&7))<<3);
    bf16x8 ph = *(const bf16x8*)&Kh[pidx];
    bf16x8 pl = *(const bf16x8*)&Kl[pidx];
    #pragma unroll
    for (int nf=0; nf<4; nf++){
      int vrow = nf*16 + l15;
      int vidx = vrow*128 + (((ks*4 + hi4) ^ (vrow&7))<<3);
      bf16x8 vh = *(const bf16x8*)&Vth[vidx];
      acc2[nf] = __builtin_amdgcn_mfma_f32_16x16x32_bf16(ph, vh, acc2[nf], 0, 0, 0);
      acc2[nf] = __builtin_amdgcn_mfma_f32_16x16x32_bf16(pl, vh, acc2[nf], 0, 0, 0);
    }
  }
  #pragma unroll
  for (int nf=0; nf<4; nf++)
    #pragma unroll
    for (int i=0;i<4;i++){
      int row = qs*64 + w*16 + hi4*4 + i;
      int col = nf*16 + l15;
      ao[(size_t)(be*128 + row)*1024 + h*64 + col] = f2bf(acc2[nf][i]);
    }
}

// ---------------- post-attention: mobius residual + LN2 roundtrip -> t (bf16) ----------------
__global__ __launch_bounds__(256) void k_postattn(const float* __restrict__ x,
    const float* __restrict__ proj, const float* __restrict__ cg,
    const float* __restrict__ lns, const float* __restrict__ lnb,
    float* __restrict__ xatt, ushort* __restrict__ tout){
  __shared__ float tmp[8];
  int r = blockIdx.x, t = threadIdx.x;
  float c = cg[0], sc = fmaxf(sqrtf(c), EPSF);
  float4 pa = ((const float4*)(proj + (size_t)r*1024))[t];
  float4 pb = ((const float4*)(proj + 1024*1024 + (size_t)r*1024))[t];
  float4 pc = ((const float4*)(proj + 2*1024*1024 + (size_t)r*1024))[t];
  float4 pd = ((const float4*)(proj + 3*1024*1024 + (size_t)r*1024))[t];
  float4 pv; pv.x=(pa.x+pb.x)+(pc.x+pd.x); pv.y=(pa.y+pb.y)+(pc.y+pd.y);
  pv.z=(pa.z+pb.z)+(pc.z+pd.z); pv.w=(pa.w+pb.w)+(pc.w+pd.w);
  float4 xv = ((const float4*)(x + (size_t)r*1024))[t];
  float pn2 = blkSum(pv.x*pv.x+pv.y*pv.y+pv.z*pv.z+pv.w*pv.w, tmp);
  float y2; float fy = expmap_factor(pn2, sc, y2);
  float ya = pv.x*fy, yb = pv.y*fy, yc = pv.z*fy, yd = pv.w*fy;
  float2 s = blkSum2(xv.x*xv.x+xv.y*xv.y+xv.z*xv.z+xv.w*xv.w,
                     xv.x*ya+xv.y*yb+xv.z*yc+xv.w*yd, tmp);
  float x2 = s.x, xy = s.y;
  float Af = 1.f + 2.f*c*xy + c*y2;
  float Bf = 1.f - c*x2;
  float den = fmaxf(1.f + 2.f*c*xy + c*c*x2*y2, EPSF);
  float num2 = fmaxf(Af*Af*x2 + 2.f*Af*Bf*xy + Bf*Bf*y2, 0.f);
  float rn = sqrtf(num2)/den;
  float fp = (rn >= 1.f) ? (ONE_M_EPS/fmaxf(rn,EPSF)) : 1.f;
  float xan = (rn >= 1.f) ? ONE_M_EPS : rn;
  float g = fp/den;
  float xa = (Af*xv.x + Bf*ya)*g;
  float xb = (Af*xv.y + Bf*yb)*g;
  float xc = (Af*xv.z + Bf*yc)*g;
  float xd = (Af*xv.w + Bf*yd)*g;
  float4 xo; xo.x=xa; xo.y=xb; xo.z=xc; xo.w=xd;
  ((float4*)(xatt + (size_t)r*1024))[t] = xo;
  float at = (rn >= 1.f) ? ATANH_1ME : atanh_c(xan);
  float fl = (xan < EPSF) ? 0.f : at / sc / fmaxf(xan, EPSF);
  float ux = xa*fl, uy = xb*fl, uz = xc*fl, uw = xd*fl;
  float2 s12 = blkSum2(ux+uy+uz+uw, ux*ux+uy*uy+uz*uz+uw*uw, tmp);
  float mu = s12.x*(1.f/1024.f);
  float var = s12.y*(1.f/1024.f) - mu*mu;
  float inv = rsqrtf(var + 1e-6f);
  float4 sv = ((const float4*)lns)[t];
  float4 bv = ((const float4*)lnb)[t];
  float ta = (ux-mu)*inv*sv.x + bv.x;
  float tb = (uy-mu)*inv*sv.y + bv.y;
  float tc = (uz-mu)*inv*sv.z + bv.z;
  float td = (uw-mu)*inv*sv.w + bv.w;
  float tn2 = blkSum(ta*ta+tb*tb+tc*tc+td*td, tmp);
  float f = roundtrip_factor(tn2, sc);
  ushort4 o; o.x=f2bf(ta*f); o.y=f2bf(tb*f); o.z=f2bf(tc*f); o.w=f2bf(td*f);
  ((ushort4*)(tout + (size_t)r*1024))[t] = o;
}

// ---------------- final: out = mobius_add(x_att, expmap0(tf)) ----------------
__global__ __launch_bounds__(256) void k_final(const float* __restrict__ xatt,
    const float* __restrict__ tf, const float* __restrict__ cg, float* __restrict__ out){
  __shared__ float tmp[8];
  int r = blockIdx.x, t = threadIdx.x;
  float c = cg[0], sc = fmaxf(sqrtf(c), EPSF);
  float4 fa = ((const float4*)(tf + (size_t)r*1024))[t];
  float4 fb = ((const float4*)(tf + 1024*1024 + (size_t)r*1024))[t];
  float4 fc = ((const float4*)(tf + 2*1024*1024 + (size_t)r*1024))[t];
  float4 fd = ((const float4*)(tf + 3*1024*1024 + (size_t)r*1024))[t];
  float4 fv; fv.x=(fa.x+fb.x)+(fc.x+fd.x); fv.y=(fa.y+fb.y)+(fc.y+fd.y);
  fv.z=(fa.z+fb.z)+(fc.z+fd.z); fv.w=(fa.w+fb.w)+(fc.w+fd.w);
  float4 xv = ((const float4*)(xatt + (size_t)r*1024))[t];
  float fn2 = blkSum(fv.x*fv.x+fv.y*fv.y+fv.z*fv.z+fv.w*fv.w, tmp);
  float y2; float fy = expmap_factor(fn2, sc, y2);
  float ya = fv.x*fy, yb = fv.y*fy, yc = fv.z*fy, yd = fv.w*fy;
  float2 s = blkSum2(xv.x*xv.x+xv.y*xv.y+xv.z*xv.z+xv.w*xv.w,
                     xv.x*ya+xv.y*yb+xv.z*yc+xv.w*yd, tmp);
  float x2 = s.x, xy = s.y;
  float Af = 1.f + 2.f*c*xy + c*y2;
  float Bf = 1.f - c*x2;
  float den = fmaxf(1.f + 2.f*c*xy + c*c*x2*y2, EPSF);
  float num2 = fmaxf(Af*Af*x2 + 2.f*Af*Bf*xy + Bf*Bf*y2, 0.f);
  float rn = sqrtf(num2)/den;
  float fp = (rn >= 1.f) ? (ONE_M_EPS/fmaxf(rn,EPSF)) : 1.f;
  float g = fp/den;
  float4 o;
  o.x = (Af*xv.x + Bf*ya)*g;
  o.y = (Af*xv.y + Bf*yb)*g;
  o.z = (Af*xv.z + Bf*yc)*g;
  o.w = (Af*xv.w + Bf*yd)*g;
  ((float4*)(out + (size_t)r*1024))[t] = o;
}

extern "C" void kernel_launch(void* const* d_in, const int* in_sizes, int n_in,
                              void* d_out, int out_size, void* d_ws, size_t ws_size,
                              hipStream_t stream){
  (void)in_sizes; (void)n_in; (void)out_size; (void)ws_size;
  const float* x     = (const float*)d_in[0];
  const float* cg    = (const float*)d_in[1];
  const float* qkv_w = (const float*)d_in[2];
  const float* qkv_b = (const float*)d_in[3];
  const float* out_w = (const float*)d_in[4];
  const float* out_b = (const float*)d_in[5];
  const float* ffn_w1= (const float*)d_in[6];
  const float* ffn_b1= (const float*)d_in[7];
  const float* ffn_w2= (const float*)d_in[8];
  const float* ffn_b2= (const float*)d_in[9];
  const float* ln1s  = (const float*)d_in[10];
  const float* ln1b  = (const float*)d_in[11];
  const float* ln2s  = (const float*)d_in[12];
  const float* ln2b  = (const float*)d_in[13];
  const float* clog  = (const float*)d_in[14];
  const float* geo   = (const float*)d_in[15];

  char* p = (char*)d_ws;
  auto take = [&](size_t n){ char* r = p; p += (n + 255) & ~(size_t)255; return r; };
  ushort* wt_qkv  = (ushort*)take((size_t)3072*1024*2);
  ushort* wt_out  = (ushort*)take((size_t)1024*1024*2);
  ushort* wt_ffn1 = (ushort*)take((size_t)4096*1024*2);
  ushort* wt_ffn2 = (ushort*)take((size_t)1024*4096*2);
  float*  bufA    = (float*)take((size_t)1024*4096*4);  // ffn1 bf16 out region
  ushort* bufB    = (ushort*)take((size_t)1024*1024*2); // x_tan ; later ao
  float*  bufC    = (float*)take((size_t)4*1024*1024*4);// split-K partials (4x 4MB)
  float*  xatt    = (float*)take((size_t)1024*1024*4);
  ushort* tbuf    = (ushort*)take((size_t)1024*1024*2);
  ushort* qhg     = (ushort*)take((size_t)1024*1024*2); // [be][h][128][64]
  ushort* qlg     = (ushort*)take((size_t)1024*1024*2);
  ushort* khg     = (ushort*)take((size_t)1024*1024*2);
  ushort* klg     = (ushort*)take((size_t)1024*1024*2);
  ushort* vhg     = (ushort*)take((size_t)1024*1024*2);
  float*  q2g     = (float*)take((size_t)16384*4);
  float*  k2g     = (float*)take((size_t)16384*4);

  k_pre<<<13312, 256, 0, stream>>>(qkv_w, out_w, ffn_w1, ffn_w2, x, cg, ln1s, ln1b,
                                   wt_qkv, wt_out, wt_ffn1, wt_ffn2, bufB);
  // qkv: BM=64 full-K (768 blocks = 3/CU) with fused rope/expmap/hi-lo epilogue -> attn tiles
  k_gemm<4><<<dim3(48,16,1), 256, 0, stream>>>(bufB, wt_qkv, qkv_b, nullptr, 1024, 3072, 1024, 1024,
                                               qhg, qlg, khg, klg, vhg, q2g, k2g, clog);
  k_attn6<<<dim3(16,8,2), 256, 0, stream>>>(qhg, qlg, khg, klg, vhg, q2g, k2g, clog, geo, bufB);
  // out-proj: BM=64 split-K4 (1024 blocks)
  k_gemm<3><<<dim3(16,16,4), 256, 0, stream>>>(bufB, wt_out, out_b, (void*)bufC, 1024, 1024, 1024, 256);
  k_postattn<<<1024, 256, 0, stream>>>(x, bufC, cg, ln2s, ln2b, xatt, tbuf);
  // ffn1: BM=64 full-K gelu (1024 blocks)
  k_gemm<2><<<dim3(64,16,1), 256, 0, stream>>>(tbuf, wt_ffn1, ffn_b1, (void*)bufA, 1024, 4096, 1024, 1024);
  // ffn2: BM=64 split-K4 (1024 blocks)
  k_gemm<3><<<dim3(16,16,4), 256, 0, stream>>>((const ushort*)bufA, wt_ffn2, ffn_b2, (void*)bufC, 1024, 1024, 4096, 1024);
  k_final<<<1024, 256, 0, stream>>>(xatt, bufC, cg, (float*)d_out);
}

// Round 15
// 109.621 us; speedup vs baseline: 1.1615x; 1.0115x over previous
//
#include <hip/hip_runtime.h>

typedef unsigned int uint;
typedef unsigned short ushort;
typedef __attribute__((ext_vector_type(8))) short bf16x8;
typedef __attribute__((ext_vector_type(4))) float f32x4;

#define EPSF 1e-7f
#define ONE_M_EPS 0.99999988079071044921875f /* f32 nearest to 1-1e-7 */
#define ATANH_1ME 8.4056213f                 /* atanh(1-1e-7), f64-accurate */
#define Y2_CLIP 0.99999982f                  /* (1-1e-7)^2 */

__device__ __forceinline__ ushort f2bf(float f){
  union{float f;uint u;}x; x.f=f; uint u=x.u;
  return (ushort)((u + 0x7fffu + ((u>>16)&1u)) >> 16);
}
__device__ __forceinline__ float bf2f(ushort u){
  union{uint u;float f;}x; x.u = ((uint)u)<<16; return x.f;
}
__device__ __forceinline__ float atanh_c(float a){
  a = fminf(a, ONE_M_EPS);
  return 0.5f*__logf((1.f+a)/(1.f-a));
}
__device__ __forceinline__ float gelu_t(float v){
  return 0.5f*v*(1.f + tanhf(0.7978845608f*(v + 0.044715f*v*v*v)));
}

__device__ __forceinline__ float expmap_factor(float n2, float sc, float& r2){
  float n = sqrtf(n2);
  if (n < EPSF) { r2 = 0.f; return 0.f; }
  float mag = tanhf(sc*n)/sc;
  float f = mag/n;
  if (mag >= 1.f) { f *= ONE_M_EPS/mag; r2 = Y2_CLIP; }
  else r2 = mag*mag;
  return f;
}
__device__ __forceinline__ float roundtrip_factor(float tn2, float sc){
  float tn = sqrtf(tn2);
  if (tn < EPSF) return 0.f;
  float mag = tanhf(sc*tn)/sc;
  if (mag >= 1.f) {
    return ATANH_1ME / (sc * tn);
  } else {
    if (mag < EPSF) return 0.f;
    return (mag/tn) * (atanh_c(mag) / (sc * mag));
  }
}

// freqs[i] = 10000^(-i/32) = 10^(-i/8), f64-derived literals
__device__ __constant__ float FREQS[32] = {
  1.0f, 0.7498942093324559f, 0.5623413251903491f, 0.4216965034285822f,
  0.31622776601683794f, 0.23713737056616552f, 0.1778279410038923f, 0.13335214321633242f,
  0.1f, 0.07498942093324558f, 0.05623413251903491f, 0.04216965034285822f,
  0.03162277660168379f, 0.023713737056616554f, 0.01778279410038923f, 0.013335214321633242f,
  0.01f, 0.007498942093324559f, 0.005623413251903491f, 0.004216965034285822f,
  0.0031622776601683794f, 0.0023713737056616554f, 0.0017782794100389228f, 0.0013335214321633241f,
  0.001f, 0.0007498942093324558f, 0.0005623413251903491f, 0.0004216965034285822f,
  0.00031622776601683794f, 0.00023713737056616553f, 0.00017782794100389227f, 0.00013335214321633243f
};

// ---------------- block reductions (256 threads) ----------------
__device__ __forceinline__ float blkSum(float v, float* tmp){
  #pragma unroll
  for (int o=32;o>0;o>>=1) v += __shfl_xor(v, o, 64);
  int w = threadIdx.x >> 6;
  if ((threadIdx.x & 63) == 0) tmp[w] = v;
  __syncthreads();
  v = tmp[0]+tmp[1]+tmp[2]+tmp[3];
  __syncthreads();
  return v;
}
__device__ __forceinline__ float2 blkSum2(float a, float b, float* tmp){
  #pragma unroll
  for (int o=32;o>0;o>>=1){ a += __shfl_xor(a, o, 64); b += __shfl_xor(b, o, 64); }
  int w = threadIdx.x >> 6;
  if ((threadIdx.x & 63) == 0){ tmp[w] = a; tmp[4+w] = b; }
  __syncthreads();
  float2 r; r.x = tmp[0]+tmp[1]+tmp[2]+tmp[3]; r.y = tmp[4]+tmp[5]+tmp[6]+tmp[7];
  __syncthreads();
  return r;
}

// ---------------- fused front-end: 4 weight transposes + prep ----------------
__global__ __launch_bounds__(256) void k_pre(const float* __restrict__ qkv_w,
    const float* __restrict__ out_w, const float* __restrict__ ffn_w1,
    const float* __restrict__ ffn_w2, const float* __restrict__ x,
    const float* __restrict__ cg, const float* __restrict__ lns, const float* __restrict__ lnb,
    ushort* __restrict__ wq, ushort* __restrict__ wo,
    ushort* __restrict__ w1, ushort* __restrict__ w2, ushort* __restrict__ xtan){
  __shared__ float s[32][33];
  int b = blockIdx.x;
  if (b < 12288){
    const float* W; ushort* WT; int K, N;
    if (b < 3072){ W=qkv_w; WT=wq; K=1024; N=3072; }
    else if (b < 4096){ b-=3072; W=out_w; WT=wo; K=1024; N=1024; }
    else if (b < 8192){ b-=4096; W=ffn_w1; WT=w1; K=1024; N=4096; }
    else { b-=8192; W=ffn_w2; WT=w2; K=4096; N=1024; }
    int nbn = N >> 5;
    int n0 = (b % nbn)*32, k0 = (b / nbn)*32;
    int tx = threadIdx.x & 31, ty = threadIdx.x >> 5; // (32,8)
    #pragma unroll
    for (int i=0;i<4;i++)
      s[ty+8*i][tx] = W[(size_t)(k0+ty+8*i)*N + n0+tx];
    __syncthreads();
    #pragma unroll
    for (int i=0;i<4;i++)
      WT[(size_t)(n0+ty+8*i)*K + k0+tx] = f2bf(s[tx][ty+8*i]);
  } else {
    float* tmp = &s[0][0];
    int r = b - 12288, t = threadIdx.x;
    float c = cg[0];
    float sc = fmaxf(sqrtf(c), EPSF);
    float4 xv = ((const float4*)(x + (size_t)r*1024))[t];
    float n2 = blkSum(xv.x*xv.x + xv.y*xv.y + xv.z*xv.z + xv.w*xv.w, tmp);
    float n = sqrtf(n2);
    float f1 = (n < EPSF) ? 0.f : (atanh_c(n) / sc / n);
    float ux = xv.x*f1, uy = xv.y*f1, uz = xv.z*f1, uw = xv.w*f1;
    float2 s12 = blkSum2(ux+uy+uz+uw, ux*ux+uy*uy+uz*uz+uw*uw, tmp);
    float mu = s12.x*(1.f/1024.f);
    float var = s12.y*(1.f/1024.f) - mu*mu;
    float inv = rsqrtf(var + 1e-6f);
    float4 sv = ((const float4*)lns)[t];
    float4 bv = ((const float4*)lnb)[t];
    float ta = (ux-mu)*inv*sv.x + bv.x;
    float tb = (uy-mu)*inv*sv.y + bv.y;
    float tc = (uz-mu)*inv*sv.z + bv.z;
    float td = (uw-mu)*inv*sv.w + bv.w;
    float tn2 = blkSum(ta*ta+tb*tb+tc*tc+td*td, tmp);
    float f = roundtrip_factor(tn2, sc);
    ushort4 o; o.x=f2bf(ta*f); o.y=f2bf(tb*f); o.z=f2bf(tc*f); o.w=f2bf(td*f);
    ((ushort4*)(xtan + (size_t)r*1024))[t] = o;
  }
}

// ---------------- GEMM: C[M][N] = A[M][K](bf16) * Bt[N][K](bf16)^T + bias ----------------
// 2-phase pipelined global_load_lds double-buffer, XOR-swizzled LDS, bijective XCD remap.
// BM=64, BN=64, 4 waves. 32KB LDS -> 4 blocks/CU (16 waves/CU TLP).
// Wave tiling: EPI 2/3 -> 32x32 (MF=2,NF=2; 4 ds_read per ks for 4 MFMA, ratio 1.0).
//              EPI 4   -> 16x64 (MF=1,NF=4; epilogue needs full head-slice per wave).
// EPI: 2 = gelu + bf16 out (z==0), 3 = f32 out at z*M*N (bias only z==0),
//      4 = qkv fused epilogue: bias + rope + expmap + hi/lo bf16 -> attn tiles (full-K, z==0)
template<int EPI>
__global__ __launch_bounds__(256) void k_gemm(const ushort* __restrict__ A,
    const ushort* __restrict__ Bt, const float* __restrict__ bias,
    void* __restrict__ C, int M, int N, int Kstride, int Kchunk,
    ushort* __restrict__ qhg = nullptr, ushort* __restrict__ qlg = nullptr,
    ushort* __restrict__ khg = nullptr, ushort* __restrict__ klg = nullptr,
    ushort* __restrict__ vhg = nullptr, float* __restrict__ q2g = nullptr,
    float* __restrict__ k2g = nullptr, const float* __restrict__ clog = nullptr){
  constexpr int MF = (EPI==4) ? 1 : 2;
  constexpr int NF = (EPI==4) ? 4 : 2;
  __shared__ ushort As[2][64*64];
  __shared__ ushort Bs[2][64*64];
  const int tid = threadIdx.x;
  const int lane = tid & 63;
  const int wid = tid >> 6;
  const int ro = (EPI==4) ? wid*16 : (wid>>1)*32;
  const int co = (EPI==4) ? 0      : (wid&1)*32;
  const int l15 = lane & 15, hi = lane >> 4;
  const int nwg = gridDim.x * gridDim.y;
  const int lin = blockIdx.y * gridDim.x + blockIdx.x;
  const int qq = nwg >> 3, rr = nwg & 7;
  const int xcd = lin & 7, ii = lin >> 3;
  const int swz = (xcd < rr) ? (xcd*(qq+1) + ii) : (rr*(qq+1) + (xcd-rr)*qq + ii);
  const int m0 = (swz % gridDim.y) * 64;
  const int n0 = (swz / gridDim.y) * 64;
  const int z = blockIdx.z;
  const int kbase = z * Kchunk;
  const int swr = (l15 & 7) << 3;

  f32x4 acc[MF][NF];
  #pragma unroll
  for (int i=0;i<MF;i++)
    #pragma unroll
    for (int j=0;j<NF;j++) acc[i][j] = (f32x4){0.f,0.f,0.f,0.f};

  auto stage = [&](int buf, int koff){
    #pragma unroll
    for (int r2=0;r2<2;r2++){
      int idx = r2*256 + tid;
      int row = idx >> 3, cc = idx & 7;
      int off = koff + ((cc ^ (row & 7)) << 3);
      int lo = (r2*256 + (tid & 192)) * 8;
      __builtin_amdgcn_global_load_lds((const __attribute__((address_space(1))) uint*)
          (A + (size_t)(m0+row)*Kstride + off),
          (__attribute__((address_space(3))) uint*)&As[buf][lo], 16, 0, 0);
      __builtin_amdgcn_global_load_lds((const __attribute__((address_space(1))) uint*)
          (Bt + (size_t)(n0+row)*Kstride + off),
          (__attribute__((address_space(3))) uint*)&Bs[buf][lo], 16, 0, 0);
    }
  };
  auto compute = [&](int buf){
    #pragma unroll
    for (int ks=0;ks<2;ks++){
      bf16x8 af[MF], bfv[NF];
      int cb = (ks*32 + hi*8) ^ swr;
      #pragma unroll
      for (int m2=0;m2<MF;m2++) af[m2]  = *(const bf16x8*)&As[buf][(ro+m2*16+l15)*64 + cb];
      #pragma unroll
      for (int n2=0;n2<NF;n2++) bfv[n2] = *(const bf16x8*)&Bs[buf][(co+n2*16+l15)*64 + cb];
      #pragma unroll
      for (int m2=0;m2<MF;m2++)
        #pragma unroll
        for (int n2=0;n2<NF;n2++)
          acc[m2][n2] = __builtin_amdgcn_mfma_f32_16x16x32_bf16(af[m2], bfv[n2], acc[m2][n2], 0, 0, 0);
    }
  };

  const int nt = Kchunk >> 6;
  stage(0, kbase);
  __syncthreads();
  int cur = 0;
  for (int t = 1; t < nt; ++t){
    stage(cur ^ 1, kbase + t*64);
    compute(cur);
    __syncthreads();
    cur ^= 1;
  }
  compute(cur);

  if (EPI == 4){
    // qkv epilogue: wave covers 16 rows x one head-slice. type: 0=Q,1=K,2=V.
    const int type = n0 >> 10;
    const int h = (n0 & 1023) >> 6;
    float v[4][4];
    #pragma unroll
    for (int n2=0;n2<4;n2++){
      float bb = bias[n0 + n2*16 + l15];
      #pragma unroll
      for (int i=0;i<4;i++) v[n2][i] = acc[0][n2 % NF][i] + bb; // NF==4 here; % keeps compile happy
    }
    if (type < 2){
      const float cl = clog[h];
      const float chh = (cl > 20.f) ? cl : log1pf(__expf(cl));
      const float sch = fmaxf(sqrtf(chh), EPSF);
      ushort* hdst = (type==0) ? qhg : khg;
      ushort* ldst = (type==0) ? qlg : klg;
      float*  sdst = (type==0) ? q2g : k2g;
      #pragma unroll
      for (int i=0;i<4;i++){
        int gr = m0 + ro + hi*4 + i;
        int r = gr & 127, be = gr >> 7;
        float fr = (float)r;
        float sn, cn;
        __sincosf(fr * FREQS[l15], &sn, &cn);
        float a = v[0][i], b = v[2][i];
        v[0][i] = a*cn - b*sn; v[2][i] = a*sn + b*cn;
        __sincosf(fr * FREQS[l15+16], &sn, &cn);
        a = v[1][i]; b = v[3][i];
        v[1][i] = a*cn - b*sn; v[3][i] = a*sn + b*cn;
        float n2s = v[0][i]*v[0][i] + v[1][i]*v[1][i] + v[2][i]*v[2][i] + v[3][i]*v[3][i];
        #pragma unroll
        for (int o=1;o<16;o<<=1) n2s += __shfl_xor(n2s, o);
        float r2; float f = expmap_factor(n2s, sch, r2);
        size_t rowbase = ((size_t)(be*16 + h)*128 + r)*64;
        #pragma unroll
        for (int n2=0;n2<4;n2++){
          float val = v[n2][i]*f;
          ushort hb = f2bf(val);
          ushort lb = f2bf(val - bf2f(hb));
          hdst[rowbase + n2*16 + l15] = hb;
          ldst[rowbase + n2*16 + l15] = lb;
        }
        if (l15 == 0) sdst[(size_t)(be*16+h)*128 + r] = r2;
      }
    } else {
      #pragma unroll
      for (int i=0;i<4;i++){
        int gr = m0 + ro + hi*4 + i;
        int r = gr & 127, be = gr >> 7;
        size_t rowbase = ((size_t)(be*16 + h)*128 + r)*64;
        #pragma unroll
        for (int n2=0;n2<4;n2++)
          vhg[rowbase + n2*16 + l15] = f2bf(v[n2][i]);
      }
    }
    return;
  }

  #pragma unroll
  for (int m=0;m<MF;m++){
    #pragma unroll
    for (int n=0;n<NF;n++){
      int gc = n0 + co + n*16 + l15;
      float bb = (EPI == 3) ? (z == 0 ? bias[gc] : 0.f) : bias[gc];
      #pragma unroll
      for (int i=0;i<4;i++){
        int gr = m0 + ro + m*16 + hi*4 + i;
        float v = acc[m][n][i] + bb;
        if (EPI == 2) v = gelu_t(v);
        if (EPI == 2) ((ushort*)C)[(size_t)gr*N + gc] = f2bf(v);
        else ((float*)C)[(size_t)z*M*N + (size_t)gr*N + gc] = v;
      }
    }
  }
}

// ---------------- MFMA hyperbolic attention v6 ----------------
// grid (H=16, Be=8, qs=2), 256 threads (4 waves). Block: 64 q-rows x 128 kv.
// All prep in the qkv GEMM epilogue; staging is pure DMA (pre-swizzled global_load_lds) + V transpose.
__global__ __launch_bounds__(256) void k_attn6(const ushort* __restrict__ qhg,
    const ushort* __restrict__ qlg, const ushort* __restrict__ khg,
    const ushort* __restrict__ klg, const ushort* __restrict__ vhg,
    const float* __restrict__ q2g, const float* __restrict__ k2g,
    const float* __restrict__ c_logits, const float* __restrict__ geo,
    ushort* __restrict__ ao){
  __shared__ ushort Kh[128*64], Kl[128*64];   // after QK^T: Ph/Pl overlay [64][128]
  __shared__ ushort Vth[64*128];              // V^T [d][kv]
  __shared__ ushort Qh[64*64], Ql[64*64];
  __shared__ float k2s[128], q2s[64];
  const int h = blockIdx.x, be = blockIdx.y, qs = blockIdx.z;
  const int tid = threadIdx.x;
  const float cl = c_logits[h];
  const float ch = (cl > 20.f) ? cl : log1pf(__expf(cl));
  const float sc = fmaxf(sqrtf(ch), EPSF);
  const float gs = geo[h];
  const size_t tbase = (size_t)(be*16 + h)*8192;   // 128*64 elements per (be,h)

  // ---- K hi/lo staging ----
  #pragma unroll
  for (int r2=0;r2<4;r2++){
    int idx = r2*256 + tid;
    int row = idx >> 3, cc = idx & 7;
    int off = row*64 + ((cc ^ (row & 7)) << 3);
    int lo = (r2*256 + (tid & 192)) * 8;
    __builtin_amdgcn_global_load_lds((const __attribute__((address_space(1))) uint*)(khg + tbase + off),
        (__attribute__((address_space(3))) uint*)&Kh[lo], 16, 0, 0);
    __builtin_amdgcn_global_load_lds((const __attribute__((address_space(1))) uint*)(klg + tbase + off),
        (__attribute__((address_space(3))) uint*)&Kl[lo], 16, 0, 0);
  }
  // ---- Q hi/lo staging (rows qs*64 .. +64) ----
  #pragma unroll
  for (int r2=0;r2<2;r2++){
    int idx = r2*256 + tid;
    int row = idx >> 3, cc = idx & 7;
    int off = (qs*64 + row)*64 + ((cc ^ (row & 7)) << 3);
    int lo = (r2*256 + (tid & 192)) * 8;
    __builtin_amdgcn_global_load_lds((const __attribute__((address_space(1))) uint*)(qhg + tbase + off),
        (__attribute__((address_space(3))) uint*)&Qh[lo], 16, 0, 0);
    __builtin_amdgcn_global_load_lds((const __attribute__((address_space(1))) uint*)(qlg + tbase + off),
        (__attribute__((address_space(3))) uint*)&Ql[lo], 16, 0, 0);
  }
  // ---- V transpose staging + norm arrays ----
  if (tid < 128){
    int kv = tid;
    const uint4* src = (const uint4*)(vhg + tbase + kv*64);
    ushort v[64];
    #pragma unroll
    for (int c2=0;c2<8;c2++) *(uint4*)&v[c2*8] = src[c2];
    #pragma unroll
    for (int d=0; d<64; d++){
      int idx = d*128 + (((kv>>3) ^ (d&7))<<3) + (kv&7);
      Vth[idx] = v[d];
    }
    k2s[kv] = k2g[(size_t)(be*16+h)*128 + kv];
  } else if (tid < 192){
    int i2 = tid - 128;
    q2s[i2] = q2g[(size_t)(be*16+h)*128 + qs*64 + i2];
  }
  __syncthreads();

  // ---- QK^T: wave w handles q local rows [w*16, w*16+16) x 128 kv; 3-pass hi/lo ----
  const int lane = tid & 63, w = tid >> 6;
  const int l15 = lane & 15, hi4 = lane >> 4;
  f32x4 acc[8];
  #pragma unroll
  for (int nf=0;nf<8;nf++) acc[nf] = (f32x4){0.f,0.f,0.f,0.f};
  #pragma unroll
  for (int ks=0; ks<2; ks++){
    int qrowL = w*16 + l15;
    int qidx = qrowL*64 + (((ks*4 + hi4) ^ (qrowL&7))<<3);
    bf16x8 qh = *(const bf16x8*)&Qh[qidx];
    bf16x8 ql2 = *(const bf16x8*)&Ql[qidx];
    #pragma unroll
    for (int nf=0; nf<8; nf++){
      int krow = nf*16 + l15;
      int kidx = krow*64 + (((ks*4 + hi4) ^ (krow&7))<<3);
      bf16x8 kh = *(const bf16x8*)&Kh[kidx];
      bf16x8 kl2 = *(const bf16x8*)&Kl[kidx];
      acc[nf] = __builtin_amdgcn_mfma_f32_16x16x32_bf16(qh, kh, acc[nf], 0, 0, 0);
      acc[nf] = __builtin_amdgcn_mfma_f32_16x16x32_bf16(qh, kl2, acc[nf], 0, 0, 0);
      acc[nf] = __builtin_amdgcn_mfma_f32_16x16x32_bf16(ql2, kh, acc[nf], 0, 0, 0);
    }
  }
  __syncthreads();   // all K reads complete -> P may overlay Kh/Kl

  // ---- distance + softmax in registers (C-layout: row=(lane>>4)*4+i, col=lane&15) ----
  float q2v[4], Bfv[4];
  #pragma unroll
  for (int i=0;i<4;i++){ q2v[i] = q2s[w*16 + hi4*4 + i]; Bfv[i] = 1.f - ch*q2v[i]; }
  const float e2 = 2.f*ch;
  #pragma unroll
  for (int nf=0; nf<8; nf++){
    float k2 = k2s[nf*16 + l15];
    #pragma unroll
    for (int i=0;i<4;i++){
      float xy = acc[nf][i];
      float Af = 1.f + ch*k2 - e2*xy;
      float den = fmaxf(Af - ch*k2*Bfv[i], EPSF);
      float num2 = fmaxf(Af*(Af*q2v[i] - 2.f*Bfv[i]*xy) + Bfv[i]*Bfv[i]*k2, 0.f);
      float rn = sqrtf(num2)/den;
      rn = (rn >= 1.f) ? ONE_M_EPS : rn;
      float arg = fminf(sc*rn, ONE_M_EPS);
      float dd = __logf((1.f+arg)/(1.f-arg)) / sc;
      acc[nf][i] = -gs*dd;
    }
  }
  #pragma unroll
  for (int i=0;i<4;i++){
    float m = acc[0][i];
    #pragma unroll
    for (int nf=1;nf<8;nf++) m = fmaxf(m, acc[nf][i]);
    #pragma unroll
    for (int o=1;o<16;o<<=1) m = fmaxf(m, __shfl_xor(m, o));
    float l = 0.f;
    #pragma unroll
    for (int nf=0;nf<8;nf++){ float pp = __expf(acc[nf][i]-m); acc[nf][i] = pp; l += pp; }
    #pragma unroll
    for (int o=1;o<16;o<<=1) l += __shfl_xor(l, o);
    float inv = 1.f/l;
    #pragma unroll
    for (int nf=0;nf<8;nf++){
      float p = acc[nf][i]*inv;
      ushort ph = f2bf(p);
      ushort pl = f2bf(p - bf2f(ph));
      int row = w*16 + hi4*4 + i, col = nf*16 + l15;
      int idx = row*128 + (((col>>3) ^ (row&7))<<3) + (col&7);
      Kh[idx] = ph; Kl[idx] = pl;
    }
  }
  __syncthreads();

  // ---- PV: ao[64][64] via MFMA, 2-pass (Ph+Pl)*Vh ----
  f32x4 acc2[4];
  #pragma unroll
  for (int nf=0;nf<4;nf++) acc2[nf] = (f32x4){0.f,0.f,0.f,0.f};
  #pragma unroll
  for (int ks=0; ks<4; ks++){
    int prow = w*16 + l15;
    int pidx = prow*128 + (((ks*4 + hi4) ^ (prow&7))<<3);
    bf16x8 ph = *(const bf16x8*)&Kh[pidx];
    bf16x8 pl = *(const bf16x8*)&Kl[pidx];
    #pragma unroll
    for (int nf=0; nf<4; nf++){
      int vrow = nf*16 + l15;
      int vidx = vrow*128 + (((ks*4 + hi4) ^ (vrow&7))<<3);
      bf16x8 vh = *(const bf16x8*)&Vth[vidx];
      acc2[nf] = __builtin_amdgcn_mfma_f32_16x16x32_bf16(ph, vh, acc2[nf], 0, 0, 0);
      acc2[nf] = __builtin_amdgcn_mfma_f32_16x16x32_bf16(pl, vh, acc2[nf], 0, 0, 0);
    }
  }
  #pragma unroll
  for (int nf=0; nf<4; nf++)
    #pragma unroll
    for (int i=0;i<4;i++){
      int row = qs*64 + w*16 + hi4*4 + i;
      int col = nf*16 + l15;
      ao[(size_t)(be*128 + row)*1024 + h*64 + col] = f2bf(acc2[nf][i]);
    }
}

// ---------------- post-attention: mobius residual + LN2 roundtrip -> t (bf16) ----------------
__global__ __launch_bounds__(256) void k_postattn(const float* __restrict__ x,
    const float* __restrict__ proj, const float* __restrict__ cg,
    const float* __restrict__ lns, const float* __restrict__ lnb,
    float* __restrict__ xatt, ushort* __restrict__ tout){
  __shared__ float tmp[8];
  int r = blockIdx.x, t = threadIdx.x;
  float c = cg[0], sc = fmaxf(sqrtf(c), EPSF);
  float4 pa = ((const float4*)(proj + (size_t)r*1024))[t];
  float4 pb = ((const float4*)(proj + 1024*1024 + (size_t)r*1024))[t];
  float4 pc = ((const float4*)(proj + 2*1024*1024 + (size_t)r*1024))[t];
  float4 pd = ((const float4*)(proj + 3*1024*1024 + (size_t)r*1024))[t];
  float4 pv; pv.x=(pa.x+pb.x)+(pc.x+pd.x); pv.y=(pa.y+pb.y)+(pc.y+pd.y);
  pv.z=(pa.z+pb.z)+(pc.z+pd.z); pv.w=(pa.w+pb.w)+(pc.w+pd.w);
  float4 xv = ((const float4*)(x + (size_t)r*1024))[t];
  float pn2 = blkSum(pv.x*pv.x+pv.y*pv.y+pv.z*pv.z+pv.w*pv.w, tmp);
  float y2; float fy = expmap_factor(pn2, sc, y2);
  float ya = pv.x*fy, yb = pv.y*fy, yc = pv.z*fy, yd = pv.w*fy;
  float2 s = blkSum2(xv.x*xv.x+xv.y*xv.y+xv.z*xv.z+xv.w*xv.w,
                     xv.x*ya+xv.y*yb+xv.z*yc+xv.w*yd, tmp);
  float x2 = s.x, xy = s.y;
  float Af = 1.f + 2.f*c*xy + c*y2;
  float Bf = 1.f - c*x2;
  float den = fmaxf(1.f + 2.f*c*xy + c*c*x2*y2, EPSF);
  float num2 = fmaxf(Af*Af*x2 + 2.f*Af*Bf*xy + Bf*Bf*y2, 0.f);
  float rn = sqrtf(num2)/den;
  float fp = (rn >= 1.f) ? (ONE_M_EPS/fmaxf(rn,EPSF)) : 1.f;
  float xan = (rn >= 1.f) ? ONE_M_EPS : rn;
  float g = fp/den;
  float xa = (Af*xv.x + Bf*ya)*g;
  float xb = (Af*xv.y + Bf*yb)*g;
  float xc = (Af*xv.z + Bf*yc)*g;
  float xd = (Af*xv.w + Bf*yd)*g;
  float4 xo; xo.x=xa; xo.y=xb; xo.z=xc; xo.w=xd;
  ((float4*)(xatt + (size_t)r*1024))[t] = xo;
  float at = (rn >= 1.f) ? ATANH_1ME : atanh_c(xan);
  float fl = (xan < EPSF) ? 0.f : at / sc / fmaxf(xan, EPSF);
  float ux = xa*fl, uy = xb*fl, uz = xc*fl, uw = xd*fl;
  float2 s12 = blkSum2(ux+uy+uz+uw, ux*ux+uy*uy+uz*uz+uw*uw, tmp);
  float mu = s12.x*(1.f/1024.f);
  float var = s12.y*(1.f/1024.f) - mu*mu;
  float inv = rsqrtf(var + 1e-6f);
  float4 sv = ((const float4*)lns)[t];
  float4 bv = ((const float4*)lnb)[t];
  float ta = (ux-mu)*inv*sv.x + bv.x;
  float tb = (uy-mu)*inv*sv.y + bv.y;
  float tc = (uz-mu)*inv*sv.z + bv.z;
  float td = (uw-mu)*inv*sv.w + bv.w;
  float tn2 = blkSum(ta*ta+tb*tb+tc*tc+td*td, tmp);
  float f = roundtrip_factor(tn2, sc);
  ushort4 o; o.x=f2bf(ta*f); o.y=f2bf(tb*f); o.z=f2bf(tc*f); o.w=f2bf(td*f);
  ((ushort4*)(tout + (size_t)r*1024))[t] = o;
}

// ---------------- final: out = mobius_add(x_att, expmap0(tf)) ----------------
__global__ __launch_bounds__(256) void k_final(const float* __restrict__ xatt,
    const float* __restrict__ tf, const float* __restrict__ cg, float* __restrict__ out){
  __shared__ float tmp[8];
  int r = blockIdx.x, t = threadIdx.x;
  float c = cg[0], sc = fmaxf(sqrtf(c), EPSF);
  float4 fa = ((const float4*)(tf + (size_t)r*1024))[t];
  float4 fb = ((const float4*)(tf + 1024*1024 + (size_t)r*1024))[t];
  float4 fc = ((const float4*)(tf + 2*1024*1024 + (size_t)r*1024))[t];
  float4 fd = ((const float4*)(tf + 3*1024*1024 + (size_t)r*1024))[t];
  float4 fv; fv.x=(fa.x+fb.x)+(fc.x+fd.x); fv.y=(fa.y+fb.y)+(fc.y+fd.y);
  fv.z=(fa.z+fb.z)+(fc.z+fd.z); fv.w=(fa.w+fb.w)+(fc.w+fd.w);
  float4 xv = ((const float4*)(xatt + (size_t)r*1024))[t];
  float fn2 = blkSum(fv.x*fv.x+fv.y*fv.y+fv.z*fv.z+fv.w*fv.w, tmp);
  float y2; float fy = expmap_factor(fn2, sc, y2);
  float ya = fv.x*fy, yb = fv.y*fy, yc = fv.z*fy, yd = fv.w*fy;
  float2 s = blkSum2(xv.x*xv.x+xv.y*xv.y+xv.z*xv.z+xv.w*xv.w,
                     xv.x*ya+xv.y*yb+xv.z*yc+xv.w*yd, tmp);
  float x2 = s.x, xy = s.y;
  float Af = 1.f + 2.f*c*xy + c*y2;
  float Bf = 1.f - c*x2;
  float den = fmaxf(1.f + 2.f*c*xy + c*c*x2*y2, EPSF);
  float num2 = fmaxf(Af*Af*x2 + 2.f*Af*Bf*xy + Bf*Bf*y2, 0.f);
  float rn = sqrtf(num2)/den;
  float fp = (rn >= 1.f) ? (ONE_M_EPS/fmaxf(rn,EPSF)) : 1.f;
  float g = fp/den;
  float4 o;
  o.x = (Af*xv.x + Bf*ya)*g;
  o.y = (Af*xv.y + Bf*yb)*g;
  o.z = (Af*xv.z + Bf*yc)*g;
  o.w = (Af*xv.w + Bf*yd)*g;
  ((float4*)(out + (size_t)r*1024))[t] = o;
}

extern "C" void kernel_launch(void* const* d_in, const int* in_sizes, int n_in,
                              void* d_out, int out_size, void* d_ws, size_t ws_size,
                              hipStream_t stream){
  (void)in_sizes; (void)n_in; (void)out_size; (void)ws_size;
  const float* x     = (const float*)d_in[0];
  const float* cg    = (const float*)d_in[1];
  const float* qkv_w = (const float*)d_in[2];
  const float* qkv_b = (const float*)d_in[3];
  const float* out_w = (const float*)d_in[4];
  const float* out_b = (const float*)d_in[5];
  const float* ffn_w1= (const float*)d_in[6];
  const float* ffn_b1= (const float*)d_in[7];
  const float* ffn_w2= (const float*)d_in[8];
  const float* ffn_b2= (const float*)d_in[9];
  const float* ln1s  = (const float*)d_in[10];
  const float* ln1b  = (const float*)d_in[11];
  const float* ln2s  = (const float*)d_in[12];
  const float* ln2b  = (const float*)d_in[13];
  const float* clog  = (const float*)d_in[14];
  const float* geo   = (const float*)d_in[15];

  char* p = (char*)d_ws;
  auto take = [&](size_t n){ char* r = p; p += (n + 255) & ~(size_t)255; return r; };
  ushort* wt_qkv  = (ushort*)take((size_t)3072*1024*2);
  ushort* wt_out  = (ushort*)take((size_t)1024*1024*2);
  ushort* wt_ffn1 = (ushort*)take((size_t)4096*1024*2);
  ushort* wt_ffn2 = (ushort*)take((size_t)1024*4096*2);
  float*  bufA    = (float*)take((size_t)1024*4096*4);  // ffn1 bf16 out region
  ushort* bufB    = (ushort*)take((size_t)1024*1024*2); // x_tan ; later ao
  float*  bufC    = (float*)take((size_t)4*1024*1024*4);// split-K partials (4x 4MB)
  float*  xatt    = (float*)take((size_t)1024*1024*4);
  ushort* tbuf    = (ushort*)take((size_t)1024*1024*2);
  ushort* qhg     = (ushort*)take((size_t)1024*1024*2); // [be][h][128][64]
  ushort* qlg     = (ushort*)take((size_t)1024*1024*2);
  ushort* khg     = (ushort*)take((size_t)1024*1024*2);
  ushort* klg     = (ushort*)take((size_t)1024*1024*2);
  ushort* vhg     = (ushort*)take((size_t)1024*1024*2);
  float*  q2g     = (float*)take((size_t)16384*4);
  float*  k2g     = (float*)take((size_t)16384*4);

  k_pre<<<13312, 256, 0, stream>>>(qkv_w, out_w, ffn_w1, ffn_w2, x, cg, ln1s, ln1b,
                                   wt_qkv, wt_out, wt_ffn1, wt_ffn2, bufB);
  // qkv: BM=64 full-K (768 blocks = 3/CU) with fused rope/expmap/hi-lo epilogue -> attn tiles
  k_gemm<4><<<dim3(48,16,1), 256, 0, stream>>>(bufB, wt_qkv, qkv_b, nullptr, 1024, 3072, 1024, 1024,
                                               qhg, qlg, khg, klg, vhg, q2g, k2g, clog);
  k_attn6<<<dim3(16,8,2), 256, 0, stream>>>(qhg, qlg, khg, klg, vhg, q2g, k2g, clog, geo, bufB);
  // out-proj: BM=64 split-K4 (1024 blocks)
  k_gemm<3><<<dim3(16,16,4), 256, 0, stream>>>(bufB, wt_out, out_b, (void*)bufC, 1024, 1024, 1024, 256);
  k_postattn<<<1024, 256, 0, stream>>>(x, bufC, cg, ln2s, ln2b, xatt, tbuf);
  // ffn1: BM=64 full-K gelu (1024 blocks)
  k_gemm<2><<<dim3(64,16,1), 256, 0, stream>>>(tbuf, wt_ffn1, ffn_b1, (void*)bufA, 1024, 4096, 1024, 1024);
  // ffn2: BM=64 split-K4 (1024 blocks)
  k_gemm<3><<<dim3(16,16,4), 256, 0, stream>>>((const ushort*)bufA, wt_ffn2, ffn_b2, (void*)bufC, 1024, 1024, 4096, 1024);
  k_final<<<1024, 256, 0, stream>>>(xatt, bufC, cg, (float*)d_out);
}